// Round 14
// baseline (10429.143 us; speedup 1.0000x reference)
//
#include <hip/hip_runtime.h>
#include <hip/hip_bf16.h>

#define SS 50
#define TT 50
#define BB 64
#define TRGV 23262
#define EE 300
#define EH 512
#define DH 1024

// generator GEMM geometry (bf16 MFMA)
#define GMRE 3136
#define GMP 3200
#define GK 1024
#define GNRE TRGV
#define GNP 23296

typedef short bf16x8 __attribute__((ext_vector_type(8)));
typedef float f32x4 __attribute__((ext_vector_type(4)));

__device__ __forceinline__ void glds16(const void* g, void* l) {
  __builtin_amdgcn_global_load_lds(
      (const __attribute__((address_space(1))) void*)g,
      (__attribute__((address_space(3))) void*)l, 16, 0, 0);
}

__device__ __forceinline__ float sigm(float x) { return 1.f / (1.f + expf(-x)); }
__device__ __forceinline__ float sum4(f32x4 v) { return v[0] + v[1] + v[2] + v[3]; }
__device__ __forceinline__ float bfu2f(unsigned short u) {
  unsigned int x = ((unsigned)u) << 16;
  return __uint_as_float(x);
}

__device__ __forceinline__ void split2(float x, __hip_bfloat16& hi, __hip_bfloat16& lo) {
  hi = __float2bfloat16(x);
  lo = __float2bfloat16(x - __bfloat162float(hi));
}

// ---- flag-array grid barrier, 64B-stride slots ----
__device__ __forceinline__ void gbarg(unsigned* arrive, unsigned* gen,
                                      int idxInGrp, int n, bool poller) {
  __syncthreads();
  unsigned g = __hip_atomic_load(gen, __ATOMIC_RELAXED, __HIP_MEMORY_SCOPE_AGENT);
  if (threadIdx.x == 0)
    __hip_atomic_store(arrive + idxInGrp * 16, g + 1u, __ATOMIC_RELEASE, __HIP_MEMORY_SCOPE_AGENT);
  if (poller) {
    int i = threadIdx.x;
    if (i < n) {
      while (__hip_atomic_load(arrive + i * 16, __ATOMIC_RELAXED, __HIP_MEMORY_SCOPE_AGENT) < g + 1u)
        __builtin_amdgcn_s_sleep(1);
      (void)__hip_atomic_load(arrive + i * 16, __ATOMIC_ACQUIRE, __HIP_MEMORY_SCOPE_AGENT);
    }
    __syncthreads();
    if (threadIdx.x == 0)
      __hip_atomic_store(gen, g + 1u, __ATOMIC_RELEASE, __HIP_MEMORY_SCOPE_AGENT);
  }
  if (threadIdx.x == 0) {
    while (__hip_atomic_load(gen, __ATOMIC_RELAXED, __HIP_MEMORY_SCOPE_AGENT) < g + 1u)
      __builtin_amdgcn_s_sleep(1);
    (void)__hip_atomic_load(gen, __ATOMIC_ACQUIRE, __HIP_MEMORY_SCOPE_AGENT);
  }
  __syncthreads();
}

__global__ void k_zero(float* __restrict__ p, long n) {
  long i = (long)blockIdx.x * 256 + threadIdx.x;
  if (i < n) p[i] = 0.f;
}
__global__ void k_zero_bf(__hip_bfloat16* __restrict__ p, long n) {
  long i = (long)blockIdx.x * 256 + threadIdx.x;
  if (i < n) p[i] = __float2bfloat16(0.f);
}

__global__ void k_embed(const int* __restrict__ src, const float* __restrict__ emb,
                        float* __restrict__ x) {
  int id = blockIdx.x * 256 + threadIdx.x;
  if (id >= SS * BB * EE) return;
  int sb = id / EE, e = id % EE;
  x[id] = emb[(long)src[sb] * EE + e];
}

__global__ void k_dbperm(const float* __restrict__ db, float* __restrict__ dbp) {
  int id = blockIdx.x * 256 + threadIdx.x;
  if (id >= 4096) return;
  int u = id >> 2, g = id & 3;
  dbp[id] = db[g * 1024 + u];
}

// fp32 [rows][ld] (+col_off) -> [rows_pad][2*Kpad] bf16 hi|lo, zero pad.
// mode 0: src=r ; 1: seq-reverse per 64 ; 2: gate-perm rp=4u+g <- g*1024+u ; 3: transpose
__global__ void k_split_pad(const float* __restrict__ in, int ld_in, int col_off,
                            int Kreal, int Kpad, int rows_real, long rows_pad,
                            int mode, __hip_bfloat16* __restrict__ out) {
  long id = (long)blockIdx.x * 256 + threadIdx.x;
  if (id >= rows_pad * Kpad) return;
  long r = id / Kpad;
  int k = id % Kpad;
  float v = 0.f;
  if (r < rows_real && k < Kreal) {
    if (mode == 3) {
      v = in[(long)k * ld_in + col_off + r];
    } else {
      long sr = r;
      if (mode == 1) sr = ((49 - (r >> 6)) << 6) + (r & 63);
      else if (mode == 2) sr = (long)(r & 3) * 1024 + (r >> 2);
      v = in[sr * ld_in + col_off + k];
    }
  }
  __hip_bfloat16 hi, lo;
  split2(v, hi, lo);
  out[r * 2 * Kpad + k] = hi;
  out[r * 2 * Kpad + Kpad + k] = lo;
}

// gather emb_de[trg[t,b]] -> split [3200][2*320]
__global__ void k_embgather_split(const int* __restrict__ trg, const float* __restrict__ emb,
                                  __hip_bfloat16* __restrict__ out) {
  long id = (long)blockIdx.x * 256 + threadIdx.x;
  if (id >= 3200L * 320) return;
  long r = id / 320;
  int k = id % 320;
  int t = r >> 6, b = r & 63;
  float v = 0.f;
  if (t < TT - 1 && k < EE) v = emb[(long)trg[t * BB + b] * EE + k];
  __hip_bfloat16 hi, lo;
  split2(v, hi, lo);
  out[r * 640 + k] = hi;
  out[r * 640 + 320 + k] = lo;
}

// plain bf16 with zero row padding (generator weight)
__global__ void k_tobf16_pad(const float* __restrict__ W, __hip_bfloat16* __restrict__ Wb,
                             long nrow_real, long nrow_pad, int K) {
  long id = (long)blockIdx.x * 256 + threadIdx.x;
  if (id >= nrow_pad * K) return;
  long r = id / K;
  Wb[id] = __float2bfloat16(r < nrow_real ? W[id] : 0.f);
}

// repack HsWo1 [3200][1024] fp32 -> HsWo1T [256 colblk][3200 row][4] bf16
__global__ void k_repackT(const float* __restrict__ in, __hip_bfloat16* __restrict__ out) {
  long id = (long)blockIdx.x * 256 + threadIdx.x;
  if (id >= 3200L * 1024) return;
  long r = id >> 10;
  int n = id & 1023;
  out[((long)(n >> 2) * 3200 + r) * 4 + (n & 3)] = __float2bfloat16(in[id]);
}

// ---- generic split-bf16 MFMA GEMM (3-pass: AhWh + AlWh + AhWl), 128x128 tile ----
template<int OUTBF>
__global__ __launch_bounds__(256) void k_gsplit(
    const __hip_bfloat16* __restrict__ A2, const __hip_bfloat16* __restrict__ W2,
    const float* __restrict__ bias, void* __restrict__ Cout,
    int Mreal, int Nreal, int ldc, int Kpad) {
  __shared__ __hip_bfloat16 As[128 * 32];
  __shared__ __hip_bfloat16 Bs[128 * 32];
  int tid = threadIdx.x, lane = tid & 63, w = tid >> 6;
  long m0 = (long)blockIdx.y * 128, n0 = (long)blockIdx.x * 128;
  int lda2 = 2 * Kpad;
  int srow = lane >> 2;
  int scol = (lane & 3) * 8;
  char* lA0 = (char*)As + w * 2048;
  char* lA1 = lA0 + 1024;
  char* lB0 = (char*)Bs + w * 2048;
  char* lB1 = lB0 + 1024;
  int wm = (w >> 1) * 64, wn = (w & 1) * 64;
  int fr = lane & 15;
  int kc = (lane >> 4) * 8;
  f32x4 acc[4][4] = {};

  for (int seg = 0; seg < 3; ++seg) {
    const __hip_bfloat16* Ab = A2 + (seg == 1 ? Kpad : 0);
    const __hip_bfloat16* Wb = W2 + (seg == 2 ? Kpad : 0);
    const __hip_bfloat16* gA0 = Ab + (m0 + w * 32 + srow) * (long)lda2 + scol;
    const __hip_bfloat16* gA1 = gA0 + 16L * lda2;
    const __hip_bfloat16* gB0 = Wb + (n0 + w * 32 + srow) * (long)lda2 + scol;
    const __hip_bfloat16* gB1 = gB0 + 16L * lda2;
    for (int kt = 0; kt < Kpad / 32; ++kt) {
      int k0 = kt * 32;
      glds16(gA0 + k0, lA0);
      glds16(gA1 + k0, lA1);
      glds16(gB0 + k0, lB0);
      glds16(gB1 + k0, lB1);
      __syncthreads();
      bf16x8 a[4], b[4];
      for (int mi = 0; mi < 4; ++mi)
        a[mi] = *(const bf16x8*)(As + (wm + mi * 16 + fr) * 32 + kc);
      for (int ni = 0; ni < 4; ++ni)
        b[ni] = *(const bf16x8*)(Bs + (wn + ni * 16 + fr) * 32 + kc);
      for (int mi = 0; mi < 4; ++mi)
        for (int ni = 0; ni < 4; ++ni)
          acc[mi][ni] = __builtin_amdgcn_mfma_f32_16x16x32_bf16(a[mi], b[ni], acc[mi][ni], 0, 0, 0);
      __syncthreads();
    }
  }

  for (int mi = 0; mi < 4; ++mi) {
    for (int ni = 0; ni < 4; ++ni) {
      int n = (int)n0 + wn + ni * 16 + (lane & 15);
      if (n >= Nreal) continue;
      float bv = bias ? bias[n] : 0.f;
      for (int r = 0; r < 4; ++r) {
        int m = (int)m0 + wm + mi * 16 + (lane >> 4) * 4 + r;
        if (m >= Mreal) continue;
        float v = acc[mi][ni][r] + bv;
        if (OUTBF) ((__hip_bfloat16*)Cout)[(long)m * ldc + n] = __float2bfloat16(v);
        else ((float*)Cout)[(long)m * ldc + n] = v;
      }
    }
  }
}

// ---- persistent encoder: Whh in LDS, split per-direction barriers ----
__global__ __launch_bounds__(512) void persist_enc(
    const float* __restrict__ xW_f, const float* __restrict__ xW_b,
    const float* __restrict__ Whf, const float* __restrict__ Whb,
    float* __restrict__ hs, float* hA, float* hB, float* hA2, float* hB2,
    float* __restrict__ cf, float* __restrict__ cb,
    float* __restrict__ hd0, float* __restrict__ cdD,
    __hip_bfloat16* __restrict__ x2A, unsigned* __restrict__ bar) {
  __shared__ float WL[16 * 516];
  int t = threadIdx.x;
  int blk = blockIdx.x;
  int dir = blk >> 7, bl = blk & 127;
  const float* Whh = dir ? Whb : Whf;
  const float* xWb0 = dir ? xW_b : xW_f;
  float* c = dir ? cb : cf;
  float* hp = dir ? hA2 : hA;
  float* hn = dir ? hB2 : hB;
  unsigned* arrG = bar + dir * 2048;
  unsigned* genG = bar + 12288 + dir * 16;
  unsigned* arrA = bar + 4096;
  unsigned* genA = bar + 12320;

  for (int idx = t; idx < 16 * 512; idx += 512) {
    int r = idx >> 9, k = idx & 511;
    int srcrow = (r & 3) * 512 + (bl * 4 + (r >> 2));
    WL[r * 516 + k] = Whh[(long)srcrow * 512 + k];
  }
  __syncthreads();

  int j = t & 15;
  int b0 = t >> 4, b1 = b0 + 32;
  int g = j & 3;
  int ju = bl * 4 + (j >> 2);
  int lbase = (t & 63) & ~3;
  const f32x4* wq = (const f32x4*)(WL + j * 516);

  for (int s = 0; s < SS; ++s) {
    const f32x4* h0q = (const f32x4*)(hp + b0 * 512);
    const f32x4* h1q = (const f32x4*)(hp + b1 * 512);
    f32x4 v0 = {0, 0, 0, 0}, v1 = {0, 0, 0, 0};
    for (int q = 0; q < 128; ++q) {
      f32x4 wv = wq[q];
      v0 += wv * h0q[q];
      v1 += wv * h1q[q];
    }
    const float* xW = xWb0 + (long)(s * BB) * 2048;
    float a0 = sum4(v0) + xW[b0 * 2048 + g * 512 + ju];
    float a1 = sum4(v1) + xW[b1 * 2048 + g * 512 + ju];
    float gi0 = __shfl(a0, lbase + 0), gf0 = __shfl(a0, lbase + 1);
    float gg0 = __shfl(a0, lbase + 2), go0 = __shfl(a0, lbase + 3);
    float gi1 = __shfl(a1, lbase + 0), gf1 = __shfl(a1, lbase + 1);
    float gg1 = __shfl(a1, lbase + 2), go1 = __shfl(a1, lbase + 3);
    if ((t & 3) == 0) {
      int hscol = dir ? (512 + ju) : ju;
      int srow = dir ? (SS - 1 - s) : s;
      long hsrow0 = (long)(srow * BB + b0) * DH + hscol;
      long hsrow1 = (long)(srow * BB + b1) * DH + hscol;
      float cn0 = sigm(gf0) * c[b0 * 512 + ju] + sigm(gi0) * tanhf(gg0);
      float hn0 = sigm(go0) * tanhf(cn0);
      c[b0 * 512 + ju] = cn0;
      hn[b0 * 512 + ju] = hn0;
      hs[hsrow0] = hn0;
      float cn1 = sigm(gf1) * c[b1 * 512 + ju] + sigm(gi1) * tanhf(gg1);
      float hn1 = sigm(go1) * tanhf(cn1);
      c[b1 * 512 + ju] = cn1;
      hn[b1 * 512 + ju] = hn1;
      hs[hsrow1] = hn1;
    }
    float* tmp = hp; hp = hn; hn = tmp;
    gbarg(arrG, genG, bl, 128, bl == 0);
  }
  gbarg(arrA, genA, blk, 256, blk == 0);
  int gid = blk * 512 + t;
  if (gid < 65536) {
    int d2 = gid >> 15, b = (gid >> 9) & 63, j2 = gid & 511;
    float hv = (d2 ? hA2 : hA)[b * 512 + j2];
    float cv = (d2 ? cb : cf)[b * 512 + j2];
    hd0[gid] = hv;
    cdD[gid] = cv;
    int bp = gid >> 10, jp = gid & 1023;
    __hip_bfloat16 hi, lo;
    split2(hv, hi, lo);
    x2A[bp * 4096 + 1024 + jp] = hi;
    x2A[bp * 4096 + 3072 + jp] = lo;
  }
}

// ---- persistent decoder v5: TC1 replaced by dedicated hWo2 register-MFMA ----
// P2 {S (blk 0..199) ∥ hWo2 (blk 200..215)} -> bar ->
// P3 {TC2: softmax + slab + hWo2 -> x ct} -> bar ->
// P4 {G-partial MFMA, x direct, W LDS} -> bar -> P1 {reduce + LSTM} -> bar.
__global__ __launch_bounds__(1024) void persist_dec(
    const float* __restrict__ G, const __hip_bfloat16* __restrict__ HsWo1T,
    const __hip_bfloat16* __restrict__ Wo22, const float* __restrict__ dWih,
    const float* __restrict__ dWhh, const __hip_bfloat16* __restrict__ Eg,
    float* __restrict__ h, float* __restrict__ hWo2,
    float* __restrict__ cd, float* __restrict__ scoresG,
    __hip_bfloat16* __restrict__ A_bf, __hip_bfloat16* __restrict__ x,
    float* __restrict__ gparts, unsigned* __restrict__ bar) {
  __shared__ __hip_bfloat16 WB[65536];  // 128 KB: [half][c16][kq4][nt4][16][8]
  __shared__ float Abuf[4096];          //  16 KB: TC partials
  int t = threadIdx.x;
  int blk = blockIdx.x;
  int w = t >> 6, lane = t & 63;
  unsigned* arrive = bar + 8192;
  unsigned* gen = bar + 12336;
  bool pol = (blk == 255);

  int nblk = blk >> 2, kchunk = blk & 3;

  // ---- load W slice (64 gate-rows x 512 k-chunk, split-bf16) into LDS ----
  for (int idx = t; idx < 64 * 512; idx += 1024) {
    int r = idx >> 9;
    int kk = idx & 511;
    int rp2 = nblk * 64 + r;
    long srcrow = (long)(rp2 & 3) * 1024 + (rp2 >> 2);
    int kabs = kchunk * 512 + kk;
    float v = (kabs < 1024) ? dWih[srcrow * 1324 + kabs]
                            : dWhh[srcrow * 1024 + (kabs - 1024)];
    __hip_bfloat16 hi, lo;
    split2(v, hi, lo);
    int c = kk >> 5, kq = (kk >> 3) & 3, e = kk & 7;
    int nt = r >> 4, rr = r & 15;
    WB[((((0 * 16 + c) * 4 + kq) * 4 + nt) * 16 + rr) * 8 + e] = hi;
    WB[((((1 * 16 + c) * 4 + kq) * 4 + nt) * 16 + rr) * 8 + e] = lo;
  }
  __syncthreads();

  int j = t & 15, b = t >> 4;
  int rp = blk * 16 + j;
  int nn = (blk & 3) * 16 + j;
  int ju = rp >> 2;
  int lbase = lane & ~3;
  const unsigned short* hwb = (const unsigned short*)HsWo1T + (long)blk * 3200 * 4;
  f32x4* Abuf4 = (f32x4*)Abuf;
  int mt = w & 3, nt = w >> 2;
  int row_a = mt * 16 + (lane & 15);
  int kq = lane >> 4;

  for (int ts = 0; ts < TT - 1; ++ts) {
    float eg = __bfloat162float(Eg[((long)(ts * BB + b)) * 4096 + rp]);

    // ---- P2: S (blocks 0..199) ∥ hWo2 (blocks 200..215) ----
    if (blk < 200) {
      int s = blk >> 2;
      int bb = (blk & 3) * 16 + (t >> 6);
      int ln = t & 63;
      const f32x4* gq = (const f32x4*)(G + ((long)s * 64 + bb) * 1024);
      const f32x4* hq = (const f32x4*)(h + bb * 1024);
      f32x4 a4 = {0, 0, 0, 0};
      #pragma unroll
      for (int q = 0; q < 4; ++q) a4 += gq[ln + q * 64] * hq[ln + q * 64];
      float p = sum4(a4);
      for (int o = 1; o < 64; o <<= 1) p += __shfl_xor(p, o);
      if (ln == 0) scoresG[s * 64 + bb] = p;
    } else if (blk < 216) {
      // hWo2[b][n] = h[b,:] . Wo2[n,:]  via 3-pass split-bf16 register MFMA
      int n0 = (blk - 200) * 64;
      int mi = w & 3, ni = w >> 2;
      int fr = lane & 15, kq2 = lane >> 4;
      const __hip_bfloat16* abase = x + (long)(mi * 16 + fr) * 4096 + kq2 * 8;
      const __hip_bfloat16* bbase = Wo22 + (long)(n0 + ni * 16 + fr) * 2048 + kq2 * 8;
      f32x4 acc = {0, 0, 0, 0};
      #pragma unroll
      for (int pass = 0; pass < 3; ++pass) {
        int aoff = (pass == 1) ? 3072 : 1024;   // Ah, Al, Ah
        int woff = (pass == 2) ? 1024 : 0;      // Wh, Wh, Wl
        #pragma unroll
        for (int ks = 0; ks < 32; ++ks) {
          bf16x8 a = *(const bf16x8*)(abase + aoff + ks * 32);
          bf16x8 bfr = *(const bf16x8*)(bbase + woff + ks * 32);
          acc = __builtin_amdgcn_mfma_f32_16x16x32_bf16(a, bfr, acc, 0, 0, 0);
        }
      }
      for (int r = 0; r < 4; ++r)
        hWo2[(mi * 16 + kq2 * 4 + r) * 1024 + n0 + ni * 16 + fr] = acc[r];
    }
    gbarg(arrive, gen, blk, 256, pol);

    // ---- P3: TC2 inline softmax + attw slab + hWo2; ct -> x ----
    {
      f32x4 z2 = {0, 0, 0, 0};
      for (int s = w; s < SS; s += 16) {
        float sc = scoresG[s * 64 + lane];
        float m = sc;
        for (int o = 32; o > 0; o >>= 1) m = fmaxf(m, __shfl_xor(m, o));
        float e = expf(sc - m);
        float su = e;
        for (int o = 32; o > 0; o >>= 1) su += __shfl_xor(su, o);
        const unsigned short* u4 = hwb + ((long)s * 64 + lane) * 4;
        f32x4 hv = {bfu2f(u4[0]), bfu2f(u4[1]), bfu2f(u4[2]), bfu2f(u4[3])};
        z2 += (e / su) * hv;
      }
      Abuf4[w * 64 + lane] = z2;
      __syncthreads();
      if (t < 256) {
        int bb = t >> 2, nl = t & 3;
        float sv = hWo2[bb * 1024 + blk * 4 + nl];
        for (int i = 0; i < 16; ++i) sv += Abuf[(i * 64 + bb) * 4 + nl];
        float ct = tanhf(sv);
        __hip_bfloat16 hi, lo;
        split2(ct, hi, lo);
        x[bb * 4096 + blk * 4 + nl] = hi;
        x[bb * 4096 + 2048 + blk * 4 + nl] = lo;
      }
    }
    gbarg(arrive, gen, blk, 256, pol);

    // ---- P4: G-partial. 3 passes {(Ah,Wh),(Ah,Wl),(Al,Wh)}, 48 MFMA/wave ----
    {
      f32x4 acc = {0, 0, 0, 0};
      const __hip_bfloat16* xrow = x + (long)row_a * 4096 + kchunk * 512 + kq * 8;
      #pragma unroll
      for (int pass = 0; pass < 3; ++pass) {
        int hh = (pass == 2) ? 1 : 0;
        int wh = (pass == 1) ? 1 : 0;
        const __hip_bfloat16* xp = xrow + hh * 2048;
        const __hip_bfloat16* wp = WB + (((wh * 16) * 4 + kq) * 4 + nt) * 16 * 8;
        #pragma unroll
        for (int c = 0; c < 16; ++c) {
          bf16x8 a = *(const bf16x8*)(xp + c * 32);
          bf16x8 bfr = *(const bf16x8*)(wp + (long)c * 4 * 4 * 16 * 8 + (lane & 15) * 8);
          acc = __builtin_amdgcn_mfma_f32_16x16x32_bf16(a, bfr, acc, 0, 0, 0);
        }
      }
      float* gp = gparts + (long)blk * 4096;
      for (int r = 0; r < 4; ++r) {
        int m = mt * 16 + kq * 4 + r;
        int n = nt * 16 + (lane & 15);
        gp[m * 64 + n] = acc[r];
      }
    }
    gbarg(arrive, gen, blk, 256, pol);

    // ---- P1 (R): reduce 4 k-chunk partials + LSTM pointwise ----
    {
      long gbase = (long)((blk >> 2) * 4) * 4096 + b * 64 + nn;
      float gv = gparts[gbase] + gparts[gbase + 4096] +
                 gparts[gbase + 2 * 4096] + gparts[gbase + 3 * 4096] + eg;
      float gi0 = __shfl(gv, lbase + 0), gf0 = __shfl(gv, lbase + 1);
      float gg0 = __shfl(gv, lbase + 2), go0 = __shfl(gv, lbase + 3);
      if ((t & 3) == 0) {
        float cn0 = sigm(gf0) * cd[b * DH + ju] + sigm(gi0) * tanhf(gg0);
        float hn0 = sigm(go0) * tanhf(cn0);
        cd[b * DH + ju] = cn0;
        h[b * DH + ju] = hn0;
        __hip_bfloat16 hi, lo;
        split2(hn0, hi, lo);
        A_bf[(long)ts * (BB * DH) + b * DH + ju] = hi;
        x[b * 4096 + 1024 + ju] = hi;
        x[b * 4096 + 3072 + ju] = lo;
      }
    }
    gbarg(arrive, gen, blk, 256, pol);
  }
}

// ---- bf16 MFMA generator GEMM (128x128 tile, m97 structure) ----
__global__ __launch_bounds__(256) void k_gen_mfma(
    const __hip_bfloat16* __restrict__ A, const __hip_bfloat16* __restrict__ Bw,
    const float* __restrict__ bias, float* __restrict__ C) {
  __shared__ __hip_bfloat16 As[128 * 32];
  __shared__ __hip_bfloat16 Bs[128 * 32];
  int tid = threadIdx.x;
  int lane = tid & 63, w = tid >> 6;
  long m0 = (long)blockIdx.y * 128, n0 = (long)blockIdx.x * 128;
  int srow = lane >> 2;
  int scol = (lane & 3) * 8;
  const __hip_bfloat16* gA0 = A + (m0 + w * 32 + srow) * GK + scol;
  const __hip_bfloat16* gA1 = gA0 + 16 * GK;
  const __hip_bfloat16* gB0 = Bw + (n0 + w * 32 + srow) * GK + scol;
  const __hip_bfloat16* gB1 = gB0 + 16 * GK;
  char* lA0 = (char*)As + w * 2048;
  char* lA1 = lA0 + 1024;
  char* lB0 = (char*)Bs + w * 2048;
  char* lB1 = lB0 + 1024;
  int wm = (w >> 1) * 64, wn = (w & 1) * 64;
  int fr = lane & 15;
  int kc = (lane >> 4) * 8;
  f32x4 acc[4][4] = {};
  for (int kt = 0; kt < GK / 32; ++kt) {
    int k0 = kt * 32;
    glds16(gA0 + k0, lA0);
    glds16(gA1 + k0, lA1);
    glds16(gB0 + k0, lB0);
    glds16(gB1 + k0, lB1);
    __syncthreads();
    bf16x8 a[4], b[4];
    for (int mi = 0; mi < 4; ++mi)
      a[mi] = *(const bf16x8*)(As + (wm + mi * 16 + fr) * 32 + kc);
    for (int ni = 0; ni < 4; ++ni)
      b[ni] = *(const bf16x8*)(Bs + (wn + ni * 16 + fr) * 32 + kc);
    for (int mi = 0; mi < 4; ++mi)
      for (int ni = 0; ni < 4; ++ni)
        acc[mi][ni] = __builtin_amdgcn_mfma_f32_16x16x32_bf16(a[mi], b[ni], acc[mi][ni], 0, 0, 0);
    __syncthreads();
  }
  for (int mi = 0; mi < 4; ++mi) {
    for (int ni = 0; ni < 4; ++ni) {
      int n = (int)n0 + wn + ni * 16 + (lane & 15);
      if (n >= GNRE) continue;
      float bv = bias[n];
      for (int r = 0; r < 4; ++r) {
        int m = (int)m0 + wm + mi * 16 + (lane >> 4) * 4 + r;
        if (m < GMRE) C[(long)m * TRGV + n] = acc[mi][ni][r] + bv;
      }
    }
  }
}

// in-place log-softmax over vocab for rows 64..3199 of out
__global__ __launch_bounds__(256) void k_logsoftmax(float* __restrict__ out) {
  int r = blockIdx.x;
  float* p = out + (long)(BB + r) * TRGV;
  int tid = threadIdx.x;
  __shared__ float red[256];
  float m = -1e30f;
  for (int i = tid; i < TRGV; i += 256) m = fmaxf(m, p[i]);
  red[tid] = m;
  __syncthreads();
  for (int s = 128; s > 0; s >>= 1) {
    if (tid < s) red[tid] = fmaxf(red[tid], red[tid + s]);
    __syncthreads();
  }
  m = red[0];
  __syncthreads();
  float sum = 0.f;
  for (int i = tid; i < TRGV; i += 256) sum += expf(p[i] - m);
  red[tid] = sum;
  __syncthreads();
  for (int s = 128; s > 0; s >>= 1) {
    if (tid < s) red[tid] += red[tid + s];
    __syncthreads();
  }
  float lse = m + logf(red[0]);
  for (int i = tid; i < TRGV; i += 256) p[i] -= lse;
}

extern "C" void kernel_launch(void* const* d_in, const int* in_sizes, int n_in,
                              void* d_out, int out_size, void* d_ws, size_t ws_size,
                              hipStream_t stream) {
  const int* src = (const int*)d_in[0];
  const int* trg = (const int*)d_in[1];
  const float* emb_en = (const float*)d_in[2];
  const float* emb_de = (const float*)d_in[3];
  const float* eWih_f = (const float*)d_in[4];
  const float* eWhh_f = (const float*)d_in[5];
  const float* eb_f = (const float*)d_in[6];
  const float* eWih_b = (const float*)d_in[7];
  const float* eWhh_b = (const float*)d_in[8];
  const float* eb_b = (const float*)d_in[9];
  const float* dWih = (const float*)d_in[10];
  const float* dWhh = (const float*)d_in[11];
  const float* db = (const float*)d_in[12];
  const float* Wgen = (const float*)d_in[13];
  const float* bgen = (const float*)d_in[14];
  const float* Wi = (const float*)d_in[15];
  const float* Wo = (const float*)d_in[16];
  float* out = (float*)d_out;

  float* base = (float*)d_ws;
  // ---- region RA (16,465,920 floats, time-multiplexed) ----
  __hip_bfloat16* xsf = (__hip_bfloat16*)base;
  __hip_bfloat16* xsb = (__hip_bfloat16*)(base + 1024000);
  __hip_bfloat16* Wihf2 = (__hip_bfloat16*)(base + 2048000);
  __hip_bfloat16* Wihb2 = (__hip_bfloat16*)(base + 2703360);
  float* xW_f = base + 3358720;
  float* xW_b = base + 9912320;
  __hip_bfloat16* hs2 = (__hip_bfloat16*)base;
  __hip_bfloat16* Wi2 = (__hip_bfloat16*)(base + 3276800);
  __hip_bfloat16* Wo12 = (__hip_bfloat16*)(base + 4325376);
  __hip_bfloat16* eg2 = (__hip_bfloat16*)(base + 5373952);
  __hip_bfloat16* Wce2 = (__hip_bfloat16*)(base + 6397952);
  __hip_bfloat16* E_g = (__hip_bfloat16*)(base + 7708672);
  __hip_bfloat16* Wgen_bf = (__hip_bfloat16*)base;   // phase 3
  // ---- region RB (persistent) ----
  float* p = base + 16465920;
  float* x_enc = p; p += SS * BB * EE;
  float* hs = p; p += (long)SS * BB * DH;
  float* G = p; p += (long)SS * BB * DH;
  float* HsWo1 = p; p += (long)SS * BB * DH;
  __hip_bfloat16* HsWo1T = (__hip_bfloat16*)p; p += (long)SS * BB * DH / 2;
  __hip_bfloat16* Wo22 = (__hip_bfloat16*)p; p += (long)DH * 2048 / 2;
  __hip_bfloat16* A_bf = (__hip_bfloat16*)p; p += (GMP * GK) / 2;
  __hip_bfloat16* x2A = (__hip_bfloat16*)p; p += (BB * 4096) / 2;
  float* gparts = p; p += 256 * 4096;
  float* hWo2 = p; p += BB * DH;
  float* dbp = p; p += 4096;
  float* scoresG = p; p += SS * BB;
  float* hd0 = p; p += BB * DH;
  float* cd = p; p += BB * DH;
  float* hA = p; p += BB * EH;
  float* hB = p; p += BB * EH;
  float* hA2 = p; p += BB * EH;
  float* hB2 = p; p += BB * EH;
  float* cf = p; p += BB * EH;
  float* cb = p; p += BB * EH;
  unsigned* bar = (unsigned*)p; p += 12352;

  dim3 b256(256);

  // ---- setup ----
  k_embed<<<dim3((SS * BB * EE + 255) / 256), b256, 0, stream>>>(src, emb_en, x_enc);
  k_zero<<<dim3((6 * BB * EH + 255) / 256), b256, 0, stream>>>(hA, 6 * BB * EH);
  k_zero<<<dim3(49), b256, 0, stream>>>((float*)bar, 12352);
  k_zero<<<dim3((int)(((long)BB * TRGV + 255) / 256)), b256, 0, stream>>>(out, (long)BB * TRGV);
  k_zero_bf<<<dim3(((GMP - GMRE) * GK + 255) / 256), b256, 0, stream>>>(
      A_bf + (long)GMRE * GK, (long)(GMP - GMRE) * GK);
  k_dbperm<<<dim3(16), b256, 0, stream>>>(db, dbp);

  // ---- encoder input: splits + split-MFMA GEMMs ----
  k_split_pad<<<dim3((3200 * 320 + 255) / 256), b256, 0, stream>>>(
      x_enc, EE, 0, EE, 320, 3200, 3200, 0, xsf);
  k_split_pad<<<dim3((3200 * 320 + 255) / 256), b256, 0, stream>>>(
      x_enc, EE, 0, EE, 320, 3200, 3200, 1, xsb);
  k_split_pad<<<dim3((2048 * 320 + 255) / 256), b256, 0, stream>>>(
      eWih_f, EE, 0, EE, 320, 2048, 2048, 0, Wihf2);
  k_split_pad<<<dim3((2048 * 320 + 255) / 256), b256, 0, stream>>>(
      eWih_b, EE, 0, EE, 320, 2048, 2048, 0, Wihb2);
  k_gsplit<0><<<dim3(16, 25), b256, 0, stream>>>(xsf, Wihf2, eb_f, xW_f, 3200, 2048, 2048, 320);
  k_gsplit<0><<<dim3(16, 25), b256, 0, stream>>>(xsb, Wihb2, eb_b, xW_b, 3200, 2048, 2048, 320);

  // ---- persistent encoder ----
  {
    void* args[] = {(void*)&xW_f, (void*)&xW_b, (void*)&eWhh_f, (void*)&eWhh_b,
                    (void*)&hs, (void*)&hA, (void*)&hB, (void*)&hA2, (void*)&hB2,
                    (void*)&cf, (void*)&cb, (void*)&hd0, (void*)&cd,
                    (void*)&x2A, (void*)&bar};
    hipLaunchCooperativeKernel((const void*)persist_enc, dim3(256), dim3(512),
                               args, 0, stream);
  }

  // ---- decoder-loop hoists ----
  k_split_pad<<<dim3((int)((3200L * 1024 + 255) / 256)), b256, 0, stream>>>(
      hs, DH, 0, DH, 1024, 3200, 3200, 0, hs2);
  k_split_pad<<<dim3((int)((1024L * 1024 + 255) / 256)), b256, 0, stream>>>(
      Wi, DH, 0, DH, 1024, 1024, 1024, 3, Wi2);
  k_split_pad<<<dim3((int)((1024L * 1024 + 255) / 256)), b256, 0, stream>>>(
      Wo, 2 * DH, 0, DH, 1024, 1024, 1024, 0, Wo12);
  k_split_pad<<<dim3((int)((1024L * 1024 + 255) / 256)), b256, 0, stream>>>(
      Wo, 2 * DH, 1024, DH, 1024, 1024, 1024, 0, Wo22);
  k_embgather_split<<<dim3((int)((3200L * 320 + 255) / 256)), b256, 0, stream>>>(
      trg, emb_de, eg2);
  k_split_pad<<<dim3((int)((4096L * 320 + 255) / 256)), b256, 0, stream>>>(
      dWih, 1324, 1024, EE, 320, 4096, 4096, 2, Wce2);
  k_gsplit<0><<<dim3(8, 25), b256, 0, stream>>>(hs2, Wi2, (const float*)nullptr, G, 3200, 1024, 1024, 1024);
  k_gsplit<0><<<dim3(8, 25), b256, 0, stream>>>(hs2, Wo12, (const float*)nullptr, HsWo1, 3200, 1024, 1024, 1024);
  k_repackT<<<dim3((int)((3200L * 1024 + 255) / 256)), b256, 0, stream>>>(HsWo1, HsWo1T);
  k_gsplit<1><<<dim3(32, 25), b256, 0, stream>>>(eg2, Wce2, dbp, E_g, 3136, 4096, 4096, 320);

  // ---- persistent decoder ----
  {
    void* args[] = {(void*)&G, (void*)&HsWo1T, (void*)&Wo22, (void*)&dWih, (void*)&dWhh,
                    (void*)&E_g, (void*)&hd0, (void*)&hWo2, (void*)&cd, (void*)&scoresG,
                    (void*)&A_bf, (void*)&x2A, (void*)&gparts, (void*)&bar};
    hipLaunchCooperativeKernel((const void*)persist_dec, dim3(256), dim3(1024),
                               args, 0, stream);
  }

  // ---- generator ----
  k_tobf16_pad<<<dim3((int)(((long)GNP * GK + 255) / 256)), b256, 0, stream>>>(
      Wgen, Wgen_bf, GNRE, GNP, GK);
  k_gen_mfma<<<dim3(GNP / 128, GMP / 128), b256, 0, stream>>>(
      A_bf, Wgen_bf, bgen, out + (long)BB * TRGV);
  k_logsoftmax<<<dim3((TT - 1) * BB), b256, 0, stream>>>(out);
}

// Round 15
// 7085.126 us; speedup vs baseline: 1.4720x; 1.4720x over previous
//
#include <hip/hip_runtime.h>
#include <hip/hip_bf16.h>

#define SS 50
#define TT 50
#define BB 64
#define TRGV 23262
#define EE 300
#define EH 512
#define DH 1024

// generator GEMM geometry (bf16 MFMA)
#define GMRE 3136
#define GMP 3200
#define GK 1024
#define GNRE TRGV
#define GNP 23296

typedef short bf16x8 __attribute__((ext_vector_type(8)));
typedef float f32x4 __attribute__((ext_vector_type(4)));

__device__ __forceinline__ void glds16(const void* g, void* l) {
  __builtin_amdgcn_global_load_lds(
      (const __attribute__((address_space(1))) void*)g,
      (__attribute__((address_space(3))) void*)l, 16, 0, 0);
}

__device__ __forceinline__ float sigm(float x) { return 1.f / (1.f + expf(-x)); }
__device__ __forceinline__ float sum4(f32x4 v) { return v[0] + v[1] + v[2] + v[3]; }
__device__ __forceinline__ float bfu2f(unsigned short u) {
  unsigned int x = ((unsigned)u) << 16;
  return __uint_as_float(x);
}

__device__ __forceinline__ void split2(float x, __hip_bfloat16& hi, __hip_bfloat16& lo) {
  hi = __float2bfloat16(x);
  lo = __float2bfloat16(x - __bfloat162float(hi));
}

// ---- flag-array grid barrier, 64B-stride slots ----
__device__ __forceinline__ void gbarg(unsigned* arrive, unsigned* gen,
                                      int idxInGrp, int n, bool poller) {
  __syncthreads();
  unsigned g = __hip_atomic_load(gen, __ATOMIC_RELAXED, __HIP_MEMORY_SCOPE_AGENT);
  if (threadIdx.x == 0)
    __hip_atomic_store(arrive + idxInGrp * 16, g + 1u, __ATOMIC_RELEASE, __HIP_MEMORY_SCOPE_AGENT);
  if (poller) {
    int i = threadIdx.x;
    if (i < n) {
      while (__hip_atomic_load(arrive + i * 16, __ATOMIC_RELAXED, __HIP_MEMORY_SCOPE_AGENT) < g + 1u)
        __builtin_amdgcn_s_sleep(1);
      (void)__hip_atomic_load(arrive + i * 16, __ATOMIC_ACQUIRE, __HIP_MEMORY_SCOPE_AGENT);
    }
    __syncthreads();
    if (threadIdx.x == 0)
      __hip_atomic_store(gen, g + 1u, __ATOMIC_RELEASE, __HIP_MEMORY_SCOPE_AGENT);
  }
  if (threadIdx.x == 0) {
    while (__hip_atomic_load(gen, __ATOMIC_RELAXED, __HIP_MEMORY_SCOPE_AGENT) < g + 1u)
      __builtin_amdgcn_s_sleep(1);
    (void)__hip_atomic_load(gen, __ATOMIC_ACQUIRE, __HIP_MEMORY_SCOPE_AGENT);
  }
  __syncthreads();
}

__global__ void k_zero(float* __restrict__ p, long n) {
  long i = (long)blockIdx.x * 256 + threadIdx.x;
  if (i < n) p[i] = 0.f;
}
__global__ void k_zero_bf(__hip_bfloat16* __restrict__ p, long n) {
  long i = (long)blockIdx.x * 256 + threadIdx.x;
  if (i < n) p[i] = __float2bfloat16(0.f);
}

__global__ void k_embed(const int* __restrict__ src, const float* __restrict__ emb,
                        float* __restrict__ x) {
  int id = blockIdx.x * 256 + threadIdx.x;
  if (id >= SS * BB * EE) return;
  int sb = id / EE, e = id % EE;
  x[id] = emb[(long)src[sb] * EE + e];
}

__global__ void k_dbperm(const float* __restrict__ db, float* __restrict__ dbp) {
  int id = blockIdx.x * 256 + threadIdx.x;
  if (id >= 4096) return;
  int u = id >> 2, g = id & 3;
  dbp[id] = db[g * 1024 + u];
}

// fp32 [rows][ld] (+col_off) -> [rows_pad][2*Kpad] bf16 hi|lo, zero pad.
// mode 0: src=r ; 1: seq-reverse per 64 ; 2: gate-perm rp=4u+g <- g*1024+u ; 3: transpose
__global__ void k_split_pad(const float* __restrict__ in, int ld_in, int col_off,
                            int Kreal, int Kpad, int rows_real, long rows_pad,
                            int mode, __hip_bfloat16* __restrict__ out) {
  long id = (long)blockIdx.x * 256 + threadIdx.x;
  if (id >= rows_pad * Kpad) return;
  long r = id / Kpad;
  int k = id % Kpad;
  float v = 0.f;
  if (r < rows_real && k < Kreal) {
    if (mode == 3) {
      v = in[(long)k * ld_in + col_off + r];
    } else {
      long sr = r;
      if (mode == 1) sr = ((49 - (r >> 6)) << 6) + (r & 63);
      else if (mode == 2) sr = (long)(r & 3) * 1024 + (r >> 2);
      v = in[sr * ld_in + col_off + k];
    }
  }
  __hip_bfloat16 hi, lo;
  split2(v, hi, lo);
  out[r * 2 * Kpad + k] = hi;
  out[r * 2 * Kpad + Kpad + k] = lo;
}

// gather emb_de[trg[t,b]] -> split [3200][2*320]
__global__ void k_embgather_split(const int* __restrict__ trg, const float* __restrict__ emb,
                                  __hip_bfloat16* __restrict__ out) {
  long id = (long)blockIdx.x * 256 + threadIdx.x;
  if (id >= 3200L * 320) return;
  long r = id / 320;
  int k = id % 320;
  int t = r >> 6, b = r & 63;
  float v = 0.f;
  if (t < TT - 1 && k < EE) v = emb[(long)trg[t * BB + b] * EE + k];
  __hip_bfloat16 hi, lo;
  split2(v, hi, lo);
  out[r * 640 + k] = hi;
  out[r * 640 + 320 + k] = lo;
}

// plain bf16 with zero row padding (generator weight)
__global__ void k_tobf16_pad(const float* __restrict__ W, __hip_bfloat16* __restrict__ Wb,
                             long nrow_real, long nrow_pad, int K) {
  long id = (long)blockIdx.x * 256 + threadIdx.x;
  if (id >= nrow_pad * K) return;
  long r = id / K;
  Wb[id] = __float2bfloat16(r < nrow_real ? W[id] : 0.f);
}

// repack HsWo1 [3200][1024] fp32 -> HsWo1T [256 colblk][3200 row][4] bf16
__global__ void k_repackT(const float* __restrict__ in, __hip_bfloat16* __restrict__ out) {
  long id = (long)blockIdx.x * 256 + threadIdx.x;
  if (id >= 3200L * 1024) return;
  long r = id >> 10;
  int n = id & 1023;
  out[((long)(n >> 2) * 3200 + r) * 4 + (n & 3)] = __float2bfloat16(in[id]);
}

// ---- generic split-bf16 MFMA GEMM (3-pass: AhWh + AlWh + AhWl), 128x128 tile ----
template<int OUTBF>
__global__ __launch_bounds__(256) void k_gsplit(
    const __hip_bfloat16* __restrict__ A2, const __hip_bfloat16* __restrict__ W2,
    const float* __restrict__ bias, void* __restrict__ Cout,
    int Mreal, int Nreal, int ldc, int Kpad) {
  __shared__ __hip_bfloat16 As[128 * 32];
  __shared__ __hip_bfloat16 Bs[128 * 32];
  int tid = threadIdx.x, lane = tid & 63, w = tid >> 6;
  long m0 = (long)blockIdx.y * 128, n0 = (long)blockIdx.x * 128;
  int lda2 = 2 * Kpad;
  int srow = lane >> 2;
  int scol = (lane & 3) * 8;
  char* lA0 = (char*)As + w * 2048;
  char* lA1 = lA0 + 1024;
  char* lB0 = (char*)Bs + w * 2048;
  char* lB1 = lB0 + 1024;
  int wm = (w >> 1) * 64, wn = (w & 1) * 64;
  int fr = lane & 15;
  int kc = (lane >> 4) * 8;
  f32x4 acc[4][4] = {};

  for (int seg = 0; seg < 3; ++seg) {
    const __hip_bfloat16* Ab = A2 + (seg == 1 ? Kpad : 0);
    const __hip_bfloat16* Wb = W2 + (seg == 2 ? Kpad : 0);
    const __hip_bfloat16* gA0 = Ab + (m0 + w * 32 + srow) * (long)lda2 + scol;
    const __hip_bfloat16* gA1 = gA0 + 16L * lda2;
    const __hip_bfloat16* gB0 = Wb + (n0 + w * 32 + srow) * (long)lda2 + scol;
    const __hip_bfloat16* gB1 = gB0 + 16L * lda2;
    for (int kt = 0; kt < Kpad / 32; ++kt) {
      int k0 = kt * 32;
      glds16(gA0 + k0, lA0);
      glds16(gA1 + k0, lA1);
      glds16(gB0 + k0, lB0);
      glds16(gB1 + k0, lB1);
      __syncthreads();
      bf16x8 a[4], b[4];
      for (int mi = 0; mi < 4; ++mi)
        a[mi] = *(const bf16x8*)(As + (wm + mi * 16 + fr) * 32 + kc);
      for (int ni = 0; ni < 4; ++ni)
        b[ni] = *(const bf16x8*)(Bs + (wn + ni * 16 + fr) * 32 + kc);
      for (int mi = 0; mi < 4; ++mi)
        for (int ni = 0; ni < 4; ++ni)
          acc[mi][ni] = __builtin_amdgcn_mfma_f32_16x16x32_bf16(a[mi], b[ni], acc[mi][ni], 0, 0, 0);
      __syncthreads();
    }
  }

  for (int mi = 0; mi < 4; ++mi) {
    for (int ni = 0; ni < 4; ++ni) {
      int n = (int)n0 + wn + ni * 16 + (lane & 15);
      if (n >= Nreal) continue;
      float bv = bias ? bias[n] : 0.f;
      for (int r = 0; r < 4; ++r) {
        int m = (int)m0 + wm + mi * 16 + (lane >> 4) * 4 + r;
        if (m >= Mreal) continue;
        float v = acc[mi][ni][r] + bv;
        if (OUTBF) ((__hip_bfloat16*)Cout)[(long)m * ldc + n] = __float2bfloat16(v);
        else ((float*)Cout)[(long)m * ldc + n] = v;
      }
    }
  }
}

// ---- persistent encoder: Whh in LDS, split per-direction barriers ----
__global__ __launch_bounds__(512) void persist_enc(
    const float* __restrict__ xW_f, const float* __restrict__ xW_b,
    const float* __restrict__ Whf, const float* __restrict__ Whb,
    float* __restrict__ hs, float* hA, float* hB, float* hA2, float* hB2,
    float* __restrict__ cf, float* __restrict__ cb,
    float* __restrict__ hd0, float* __restrict__ hT0, float* __restrict__ cdD,
    __hip_bfloat16* __restrict__ x2A, unsigned* __restrict__ bar) {
  __shared__ float WL[16 * 516];
  int t = threadIdx.x;
  int blk = blockIdx.x;
  int dir = blk >> 7, bl = blk & 127;
  const float* Whh = dir ? Whb : Whf;
  const float* xWb0 = dir ? xW_b : xW_f;
  float* c = dir ? cb : cf;
  float* hp = dir ? hA2 : hA;
  float* hn = dir ? hB2 : hB;
  unsigned* arrG = bar + dir * 2048;
  unsigned* genG = bar + 12288 + dir * 16;
  unsigned* arrA = bar + 4096;
  unsigned* genA = bar + 12320;

  for (int idx = t; idx < 16 * 512; idx += 512) {
    int r = idx >> 9, k = idx & 511;
    int srcrow = (r & 3) * 512 + (bl * 4 + (r >> 2));
    WL[r * 516 + k] = Whh[(long)srcrow * 512 + k];
  }
  __syncthreads();

  int j = t & 15;
  int b0 = t >> 4, b1 = b0 + 32;
  int g = j & 3;
  int ju = bl * 4 + (j >> 2);
  int lbase = (t & 63) & ~3;
  const f32x4* wq = (const f32x4*)(WL + j * 516);

  for (int s = 0; s < SS; ++s) {
    const f32x4* h0q = (const f32x4*)(hp + b0 * 512);
    const f32x4* h1q = (const f32x4*)(hp + b1 * 512);
    f32x4 v0 = {0, 0, 0, 0}, v1 = {0, 0, 0, 0};
    for (int q = 0; q < 128; ++q) {
      f32x4 wv = wq[q];
      v0 += wv * h0q[q];
      v1 += wv * h1q[q];
    }
    const float* xW = xWb0 + (long)(s * BB) * 2048;
    float a0 = sum4(v0) + xW[b0 * 2048 + g * 512 + ju];
    float a1 = sum4(v1) + xW[b1 * 2048 + g * 512 + ju];
    float gi0 = __shfl(a0, lbase + 0), gf0 = __shfl(a0, lbase + 1);
    float gg0 = __shfl(a0, lbase + 2), go0 = __shfl(a0, lbase + 3);
    float gi1 = __shfl(a1, lbase + 0), gf1 = __shfl(a1, lbase + 1);
    float gg1 = __shfl(a1, lbase + 2), go1 = __shfl(a1, lbase + 3);
    if ((t & 3) == 0) {
      int hscol = dir ? (512 + ju) : ju;
      int srow = dir ? (SS - 1 - s) : s;
      long hsrow0 = (long)(srow * BB + b0) * DH + hscol;
      long hsrow1 = (long)(srow * BB + b1) * DH + hscol;
      float cn0 = sigm(gf0) * c[b0 * 512 + ju] + sigm(gi0) * tanhf(gg0);
      float hn0 = sigm(go0) * tanhf(cn0);
      c[b0 * 512 + ju] = cn0;
      hn[b0 * 512 + ju] = hn0;
      hs[hsrow0] = hn0;
      float cn1 = sigm(gf1) * c[b1 * 512 + ju] + sigm(gi1) * tanhf(gg1);
      float hn1 = sigm(go1) * tanhf(cn1);
      c[b1 * 512 + ju] = cn1;
      hn[b1 * 512 + ju] = hn1;
      hs[hsrow1] = hn1;
    }
    float* tmp = hp; hp = hn; hn = tmp;
    gbarg(arrG, genG, bl, 128, bl == 0);
  }
  gbarg(arrA, genA, blk, 256, blk == 0);
  int gid = blk * 512 + t;
  if (gid < 65536) {
    int d2 = gid >> 15, b = (gid >> 9) & 63, j2 = gid & 511;
    float hv = (d2 ? hA2 : hA)[b * 512 + j2];
    float cv = (d2 ? cb : cf)[b * 512 + j2];
    hd0[gid] = hv;
    cdD[gid] = cv;
    int bp = gid >> 10, jp = gid & 1023;
    hT0[jp * 64 + bp] = hv;
    __hip_bfloat16 hi, lo;
    split2(hv, hi, lo);
    x2A[bp * 4096 + 1024 + jp] = hi;
    x2A[bp * 4096 + 3072 + jp] = lo;
  }
}

// ---- persistent decoder v6: v4 + k-chunked TC1 (coalesced, no straggler) ----
// 256 blocks = 64 n-groups x 4 k-chunks. Per step:
// P2 {S (200 blk) ∥ TC1 k-chunked: cols nb*16..+15, k slice -> ctparts} -> bar ->
// P3 {TC2: softmax + slab + ctparts reduce -> x ct} -> bar ->
// P4 {G-partial MFMA, x direct (own k-chunk), W LDS} -> bar ->
// P1 {reduce gparts + LSTM -> h, hT, x h-slots, A_bf} -> bar.
__global__ __launch_bounds__(1024) void persist_dec(
    const float* __restrict__ G, const __hip_bfloat16* __restrict__ HsWo1T,
    const float* __restrict__ Wo, const float* __restrict__ dWih,
    const float* __restrict__ dWhh, const __hip_bfloat16* __restrict__ Eg,
    float* __restrict__ h, float* __restrict__ hT,
    float* __restrict__ cd, float* __restrict__ scoresG,
    __hip_bfloat16* __restrict__ A_bf, __hip_bfloat16* __restrict__ x,
    float* __restrict__ gparts, float* __restrict__ ctparts,
    unsigned* __restrict__ bar) {
  __shared__ __hip_bfloat16 WB[65536];  // 128 KB: [half][c16][kq4][nt4][16][8]
  __shared__ float Abuf[4096];          //  16 KB: TC partials
  int t = threadIdx.x;
  int blk = blockIdx.x;
  int w = t >> 6, lane = t & 63;
  unsigned* arrive = bar + 8192;
  unsigned* gen = bar + 12336;
  bool pol = (blk == 255);

  int nblk = blk >> 2, kchunk = blk & 3;

  // ---- load W slice (64 gate-rows x 512 k-chunk, split-bf16) into LDS ----
  for (int idx = t; idx < 64 * 512; idx += 1024) {
    int r = idx >> 9;
    int kk = idx & 511;
    int rp2 = nblk * 64 + r;
    long srcrow = (long)(rp2 & 3) * 1024 + (rp2 >> 2);
    int kabs = kchunk * 512 + kk;
    float v = (kabs < 1024) ? dWih[srcrow * 1324 + kabs]
                            : dWhh[srcrow * 1024 + (kabs - 1024)];
    __hip_bfloat16 hi, lo;
    split2(v, hi, lo);
    int c = kk >> 5, kq = (kk >> 3) & 3, e = kk & 7;
    int nt = r >> 4, rr = r & 15;
    WB[((((0 * 16 + c) * 4 + kq) * 4 + nt) * 16 + rr) * 8 + e] = hi;
    WB[((((1 * 16 + c) * 4 + kq) * 4 + nt) * 16 + rr) * 8 + e] = lo;
  }
  __syncthreads();

  int j = t & 15, b = t >> 4;
  int rp = blk * 16 + j;
  int nn = (blk & 3) * 16 + j;
  int ju = rp >> 2;
  int lbase = lane & ~3;
  const unsigned short* hwb = (const unsigned short*)HsWo1T + (long)blk * 3200 * 4;
  f32x4* Abuf4 = (f32x4*)Abuf;
  int mt = w & 3, nt = w >> 2;
  int row_a = mt * 16 + (lane & 15);
  int kq = lane >> 4;
  // k-chunked TC1 role: cols nblk*16 + cg*4 .. +3 ; k in kchunk*256 + ks*64 .. +64
  int cg = w >> 2, ks = w & 3;
  const float* wo2c = Wo + (long)(nblk * 16 + cg * 4) * 2048 + 1024 + kchunk * 256;

  for (int ts = 0; ts < TT - 1; ++ts) {
    float eg = __bfloat162float(Eg[((long)(ts * BB + b)) * 4096 + rp]);

    // ---- P2: S (blocks 0..199) ∥ k-chunked TC1 (all blocks) ----
    if (blk < 200) {
      int s = blk >> 2;
      int bb = (blk & 3) * 16 + (t >> 6);
      int ln = t & 63;
      const f32x4* gq = (const f32x4*)(G + ((long)s * 64 + bb) * 1024);
      const f32x4* hq = (const f32x4*)(h + bb * 1024);
      f32x4 a4 = {0, 0, 0, 0};
      #pragma unroll
      for (int q = 0; q < 4; ++q) a4 += gq[ln + q * 64] * hq[ln + q * 64];
      float p = sum4(a4);
      for (int o = 1; o < 64; o <<= 1) p += __shfl_xor(p, o);
      if (ln == 0) scoresG[s * 64 + bb] = p;
    }
    {
      f32x4 z1 = {0, 0, 0, 0};
      for (int k = ks * 64; k < ks * 64 + 64; ++k) {
        float hb = hT[(kchunk * 256 + k) * 64 + lane];
        f32x4 wv = {wo2c[k], wo2c[2048 + k], wo2c[4096 + k], wo2c[6144 + k]};
        z1 += hb * wv;
      }
      Abuf4[w * 64 + lane] = z1;   // [cg][ks][b] quad
      __syncthreads();
      // reduce over ks (4) -> ctparts[kchunk][b][nblk*16 + cg*4 + nl]
      int cg2 = t >> 8, bb = (t >> 2) & 63, nl = t & 3;
      float sv = 0.f;
      for (int i = 0; i < 4; ++i) sv += Abuf[((cg2 * 4 + i) * 64 + bb) * 4 + nl];
      ctparts[((long)kchunk * 64 + bb) * 1024 + nblk * 16 + cg2 * 4 + nl] = sv;
    }
    gbarg(arrive, gen, blk, 256, pol);

    // ---- P3: TC2 inline softmax + attw slab + ctparts reduce; ct -> x ----
    {
      f32x4 z2 = {0, 0, 0, 0};
      for (int s = w; s < SS; s += 16) {
        float sc = scoresG[s * 64 + lane];
        float m = sc;
        for (int o = 32; o > 0; o >>= 1) m = fmaxf(m, __shfl_xor(m, o));
        float e = expf(sc - m);
        float su = e;
        for (int o = 32; o > 0; o >>= 1) su += __shfl_xor(su, o);
        const unsigned short* u4 = hwb + ((long)s * 64 + lane) * 4;
        f32x4 hv = {bfu2f(u4[0]), bfu2f(u4[1]), bfu2f(u4[2]), bfu2f(u4[3])};
        z2 += (e / su) * hv;
      }
      Abuf4[w * 64 + lane] = z2;
      __syncthreads();
      if (t < 256) {
        int bb = t >> 2, nl = t & 3;
        int col = blk * 4 + nl;
        float sv = ctparts[((long)0 * 64 + bb) * 1024 + col]
                 + ctparts[((long)1 * 64 + bb) * 1024 + col]
                 + ctparts[((long)2 * 64 + bb) * 1024 + col]
                 + ctparts[((long)3 * 64 + bb) * 1024 + col];
        for (int i = 0; i < 16; ++i) sv += Abuf[(i * 64 + bb) * 4 + nl];
        float ct = tanhf(sv);
        __hip_bfloat16 hi, lo;
        split2(ct, hi, lo);
        x[bb * 4096 + blk * 4 + nl] = hi;
        x[bb * 4096 + 2048 + blk * 4 + nl] = lo;
      }
    }
    gbarg(arrive, gen, blk, 256, pol);

    // ---- P4: G-partial. 3 passes {(Ah,Wh),(Ah,Wl),(Al,Wh)}, 48 MFMA/wave ----
    {
      f32x4 acc = {0, 0, 0, 0};
      const __hip_bfloat16* xrow = x + (long)row_a * 4096 + kchunk * 512 + kq * 8;
      #pragma unroll
      for (int pass = 0; pass < 3; ++pass) {
        int hh = (pass == 2) ? 1 : 0;
        int wh = (pass == 1) ? 1 : 0;
        const __hip_bfloat16* xp = xrow + hh * 2048;
        const __hip_bfloat16* wp = WB + (((wh * 16) * 4 + kq) * 4 + nt) * 16 * 8;
        #pragma unroll
        for (int c = 0; c < 16; ++c) {
          bf16x8 a = *(const bf16x8*)(xp + c * 32);
          bf16x8 bfr = *(const bf16x8*)(wp + (long)c * 4 * 4 * 16 * 8 + (lane & 15) * 8);
          acc = __builtin_amdgcn_mfma_f32_16x16x32_bf16(a, bfr, acc, 0, 0, 0);
        }
      }
      float* gp = gparts + (long)blk * 4096;
      for (int r = 0; r < 4; ++r) {
        int m = mt * 16 + kq * 4 + r;
        int n = nt * 16 + (lane & 15);
        gp[m * 64 + n] = acc[r];
      }
    }
    gbarg(arrive, gen, blk, 256, pol);

    // ---- P1 (R): reduce 4 k-chunk partials + LSTM pointwise ----
    {
      long gbase = (long)((blk >> 2) * 4) * 4096 + b * 64 + nn;
      float gv = gparts[gbase] + gparts[gbase + 4096] +
                 gparts[gbase + 2 * 4096] + gparts[gbase + 3 * 4096] + eg;
      float gi0 = __shfl(gv, lbase + 0), gf0 = __shfl(gv, lbase + 1);
      float gg0 = __shfl(gv, lbase + 2), go0 = __shfl(gv, lbase + 3);
      if ((t & 3) == 0) {
        float cn0 = sigm(gf0) * cd[b * DH + ju] + sigm(gi0) * tanhf(gg0);
        float hn0 = sigm(go0) * tanhf(cn0);
        cd[b * DH + ju] = cn0;
        h[b * DH + ju] = hn0;
        hT[ju * 64 + b] = hn0;
        __hip_bfloat16 hi, lo;
        split2(hn0, hi, lo);
        A_bf[(long)ts * (BB * DH) + b * DH + ju] = hi;
        x[b * 4096 + 1024 + ju] = hi;
        x[b * 4096 + 3072 + ju] = lo;
      }
    }
    gbarg(arrive, gen, blk, 256, pol);
  }
}

// ---- bf16 MFMA generator GEMM (128x128 tile, m97 structure) ----
__global__ __launch_bounds__(256) void k_gen_mfma(
    const __hip_bfloat16* __restrict__ A, const __hip_bfloat16* __restrict__ Bw,
    const float* __restrict__ bias, float* __restrict__ C) {
  __shared__ __hip_bfloat16 As[128 * 32];
  __shared__ __hip_bfloat16 Bs[128 * 32];
  int tid = threadIdx.x;
  int lane = tid & 63, w = tid >> 6;
  long m0 = (long)blockIdx.y * 128, n0 = (long)blockIdx.x * 128;
  int srow = lane >> 2;
  int scol = (lane & 3) * 8;
  const __hip_bfloat16* gA0 = A + (m0 + w * 32 + srow) * GK + scol;
  const __hip_bfloat16* gA1 = gA0 + 16 * GK;
  const __hip_bfloat16* gB0 = Bw + (n0 + w * 32 + srow) * GK + scol;
  const __hip_bfloat16* gB1 = gB0 + 16 * GK;
  char* lA0 = (char*)As + w * 2048;
  char* lA1 = lA0 + 1024;
  char* lB0 = (char*)Bs + w * 2048;
  char* lB1 = lB0 + 1024;
  int wm = (w >> 1) * 64, wn = (w & 1) * 64;
  int fr = lane & 15;
  int kc = (lane >> 4) * 8;
  f32x4 acc[4][4] = {};
  for (int kt = 0; kt < GK / 32; ++kt) {
    int k0 = kt * 32;
    glds16(gA0 + k0, lA0);
    glds16(gA1 + k0, lA1);
    glds16(gB0 + k0, lB0);
    glds16(gB1 + k0, lB1);
    __syncthreads();
    bf16x8 a[4], b[4];
    for (int mi = 0; mi < 4; ++mi)
      a[mi] = *(const bf16x8*)(As + (wm + mi * 16 + fr) * 32 + kc);
    for (int ni = 0; ni < 4; ++ni)
      b[ni] = *(const bf16x8*)(Bs + (wn + ni * 16 + fr) * 32 + kc);
    for (int mi = 0; mi < 4; ++mi)
      for (int ni = 0; ni < 4; ++ni)
        acc[mi][ni] = __builtin_amdgcn_mfma_f32_16x16x32_bf16(a[mi], b[ni], acc[mi][ni], 0, 0, 0);
    __syncthreads();
  }
  for (int mi = 0; mi < 4; ++mi) {
    for (int ni = 0; ni < 4; ++ni) {
      int n = (int)n0 + wn + ni * 16 + (lane & 15);
      if (n >= GNRE) continue;
      float bv = bias[n];
      for (int r = 0; r < 4; ++r) {
        int m = (int)m0 + wm + mi * 16 + (lane >> 4) * 4 + r;
        if (m < GMRE) C[(long)m * TRGV + n] = acc[mi][ni][r] + bv;
      }
    }
  }
}

// in-place log-softmax over vocab for rows 64..3199 of out
__global__ __launch_bounds__(256) void k_logsoftmax(float* __restrict__ out) {
  int r = blockIdx.x;
  float* p = out + (long)(BB + r) * TRGV;
  int tid = threadIdx.x;
  __shared__ float red[256];
  float m = -1e30f;
  for (int i = tid; i < TRGV; i += 256) m = fmaxf(m, p[i]);
  red[tid] = m;
  __syncthreads();
  for (int s = 128; s > 0; s >>= 1) {
    if (tid < s) red[tid] = fmaxf(red[tid], red[tid + s]);
    __syncthreads();
  }
  m = red[0];
  __syncthreads();
  float sum = 0.f;
  for (int i = tid; i < TRGV; i += 256) sum += expf(p[i] - m);
  red[tid] = sum;
  __syncthreads();
  for (int s = 128; s > 0; s >>= 1) {
    if (tid < s) red[tid] += red[tid + s];
    __syncthreads();
  }
  float lse = m + logf(red[0]);
  for (int i = tid; i < TRGV; i += 256) p[i] -= lse;
}

extern "C" void kernel_launch(void* const* d_in, const int* in_sizes, int n_in,
                              void* d_out, int out_size, void* d_ws, size_t ws_size,
                              hipStream_t stream) {
  const int* src = (const int*)d_in[0];
  const int* trg = (const int*)d_in[1];
  const float* emb_en = (const float*)d_in[2];
  const float* emb_de = (const float*)d_in[3];
  const float* eWih_f = (const float*)d_in[4];
  const float* eWhh_f = (const float*)d_in[5];
  const float* eb_f = (const float*)d_in[6];
  const float* eWih_b = (const float*)d_in[7];
  const float* eWhh_b = (const float*)d_in[8];
  const float* eb_b = (const float*)d_in[9];
  const float* dWih = (const float*)d_in[10];
  const float* dWhh = (const float*)d_in[11];
  const float* db = (const float*)d_in[12];
  const float* Wgen = (const float*)d_in[13];
  const float* bgen = (const float*)d_in[14];
  const float* Wi = (const float*)d_in[15];
  const float* Wo = (const float*)d_in[16];
  float* out = (float*)d_out;

  float* base = (float*)d_ws;
  // ---- region RA (16,465,920 floats, time-multiplexed) ----
  __hip_bfloat16* xsf = (__hip_bfloat16*)base;
  __hip_bfloat16* xsb = (__hip_bfloat16*)(base + 1024000);
  __hip_bfloat16* Wihf2 = (__hip_bfloat16*)(base + 2048000);
  __hip_bfloat16* Wihb2 = (__hip_bfloat16*)(base + 2703360);
  float* xW_f = base + 3358720;
  float* xW_b = base + 9912320;
  __hip_bfloat16* hs2 = (__hip_bfloat16*)base;
  __hip_bfloat16* Wi2 = (__hip_bfloat16*)(base + 3276800);
  __hip_bfloat16* Wo12 = (__hip_bfloat16*)(base + 4325376);
  __hip_bfloat16* eg2 = (__hip_bfloat16*)(base + 5373952);
  __hip_bfloat16* Wce2 = (__hip_bfloat16*)(base + 6397952);
  __hip_bfloat16* E_g = (__hip_bfloat16*)(base + 7708672);
  __hip_bfloat16* Wgen_bf = (__hip_bfloat16*)base;   // phase 3
  // ---- region RB (persistent) ----
  float* p = base + 16465920;
  float* x_enc = p; p += SS * BB * EE;
  float* hs = p; p += (long)SS * BB * DH;
  float* G = p; p += (long)SS * BB * DH;
  float* HsWo1 = p; p += (long)SS * BB * DH;
  __hip_bfloat16* HsWo1T = (__hip_bfloat16*)p; p += (long)SS * BB * DH / 2;
  __hip_bfloat16* A_bf = (__hip_bfloat16*)p; p += (GMP * GK) / 2;
  __hip_bfloat16* x2A = (__hip_bfloat16*)p; p += (BB * 4096) / 2;
  float* gparts = p; p += 256 * 4096;
  float* ctparts = p; p += 4 * BB * DH;
  float* dbp = p; p += 4096;
  float* scoresG = p; p += SS * BB;
  float* hd0 = p; p += BB * DH;
  float* hT0 = p; p += BB * DH;
  float* cd = p; p += BB * DH;
  float* hA = p; p += BB * EH;
  float* hB = p; p += BB * EH;
  float* hA2 = p; p += BB * EH;
  float* hB2 = p; p += BB * EH;
  float* cf = p; p += BB * EH;
  float* cb = p; p += BB * EH;
  unsigned* bar = (unsigned*)p; p += 12352;

  dim3 b256(256);

  // ---- setup ----
  k_embed<<<dim3((SS * BB * EE + 255) / 256), b256, 0, stream>>>(src, emb_en, x_enc);
  k_zero<<<dim3((6 * BB * EH + 255) / 256), b256, 0, stream>>>(hA, 6 * BB * EH);
  k_zero<<<dim3(49), b256, 0, stream>>>((float*)bar, 12352);
  k_zero<<<dim3((int)(((long)BB * TRGV + 255) / 256)), b256, 0, stream>>>(out, (long)BB * TRGV);
  k_zero_bf<<<dim3(((GMP - GMRE) * GK + 255) / 256), b256, 0, stream>>>(
      A_bf + (long)GMRE * GK, (long)(GMP - GMRE) * GK);
  k_dbperm<<<dim3(16), b256, 0, stream>>>(db, dbp);

  // ---- encoder input: splits + split-MFMA GEMMs ----
  k_split_pad<<<dim3((3200 * 320 + 255) / 256), b256, 0, stream>>>(
      x_enc, EE, 0, EE, 320, 3200, 3200, 0, xsf);
  k_split_pad<<<dim3((3200 * 320 + 255) / 256), b256, 0, stream>>>(
      x_enc, EE, 0, EE, 320, 3200, 3200, 1, xsb);
  k_split_pad<<<dim3((2048 * 320 + 255) / 256), b256, 0, stream>>>(
      eWih_f, EE, 0, EE, 320, 2048, 2048, 0, Wihf2);
  k_split_pad<<<dim3((2048 * 320 + 255) / 256), b256, 0, stream>>>(
      eWih_b, EE, 0, EE, 320, 2048, 2048, 0, Wihb2);
  k_gsplit<0><<<dim3(16, 25), b256, 0, stream>>>(xsf, Wihf2, eb_f, xW_f, 3200, 2048, 2048, 320);
  k_gsplit<0><<<dim3(16, 25), b256, 0, stream>>>(xsb, Wihb2, eb_b, xW_b, 3200, 2048, 2048, 320);

  // ---- persistent encoder ----
  {
    void* args[] = {(void*)&xW_f, (void*)&xW_b, (void*)&eWhh_f, (void*)&eWhh_b,
                    (void*)&hs, (void*)&hA, (void*)&hB, (void*)&hA2, (void*)&hB2,
                    (void*)&cf, (void*)&cb, (void*)&hd0, (void*)&hT0, (void*)&cd,
                    (void*)&x2A, (void*)&bar};
    hipLaunchCooperativeKernel((const void*)persist_enc, dim3(256), dim3(512),
                               args, 0, stream);
  }

  // ---- decoder-loop hoists ----
  k_split_pad<<<dim3((int)((3200L * 1024 + 255) / 256)), b256, 0, stream>>>(
      hs, DH, 0, DH, 1024, 3200, 3200, 0, hs2);
  k_split_pad<<<dim3((int)((1024L * 1024 + 255) / 256)), b256, 0, stream>>>(
      Wi, DH, 0, DH, 1024, 1024, 1024, 3, Wi2);
  k_split_pad<<<dim3((int)((1024L * 1024 + 255) / 256)), b256, 0, stream>>>(
      Wo, 2 * DH, 0, DH, 1024, 1024, 1024, 0, Wo12);
  k_embgather_split<<<dim3((int)((3200L * 320 + 255) / 256)), b256, 0, stream>>>(
      trg, emb_de, eg2);
  k_split_pad<<<dim3((int)((4096L * 320 + 255) / 256)), b256, 0, stream>>>(
      dWih, 1324, 1024, EE, 320, 4096, 4096, 2, Wce2);
  k_gsplit<0><<<dim3(8, 25), b256, 0, stream>>>(hs2, Wi2, (const float*)nullptr, G, 3200, 1024, 1024, 1024);
  k_gsplit<0><<<dim3(8, 25), b256, 0, stream>>>(hs2, Wo12, (const float*)nullptr, HsWo1, 3200, 1024, 1024, 1024);
  k_repackT<<<dim3((int)((3200L * 1024 + 255) / 256)), b256, 0, stream>>>(HsWo1, HsWo1T);
  k_gsplit<1><<<dim3(32, 25), b256, 0, stream>>>(eg2, Wce2, dbp, E_g, 3136, 4096, 4096, 320);

  // ---- persistent decoder ----
  {
    void* args[] = {(void*)&G, (void*)&HsWo1T, (void*)&Wo, (void*)&dWih, (void*)&dWhh,
                    (void*)&E_g, (void*)&hd0, (void*)&hT0, (void*)&cd, (void*)&scoresG,
                    (void*)&A_bf, (void*)&x2A, (void*)&gparts, (void*)&ctparts,
                    (void*)&bar};
    hipLaunchCooperativeKernel((const void*)persist_dec, dim3(256), dim3(1024),
                               args, 0, stream);
  }

  // ---- generator ----
  k_tobf16_pad<<<dim3((int)(((long)GNP * GK + 255) / 256)), b256, 0, stream>>>(
      Wgen, Wgen_bf, GNRE, GNP, GK);
  k_gen_mfma<<<dim3(GNP / 128, GMP / 128), b256, 0, stream>>>(
      A_bf, Wgen_bf, bgen, out + (long)BB * TRGV);
  k_logsoftmax<<<dim3((TT - 1) * BB), b256, 0, stream>>>(out);
}

// Round 16
// 6417.243 us; speedup vs baseline: 1.6252x; 1.1041x over previous
//
#include <hip/hip_runtime.h>
#include <hip/hip_bf16.h>

#define SS 50
#define TT 50
#define BB 64
#define TRGV 23262
#define EE 300
#define EH 512
#define DH 1024

// generator GEMM geometry (bf16 MFMA)
#define GMRE 3136
#define GMP 3200
#define GK 1024
#define GNRE TRGV
#define GNP 23296

typedef short bf16x8 __attribute__((ext_vector_type(8)));
typedef float f32x4 __attribute__((ext_vector_type(4)));
typedef unsigned short u16x4 __attribute__((ext_vector_type(4)));

__device__ __forceinline__ void glds16(const void* g, void* l) {
  __builtin_amdgcn_global_load_lds(
      (const __attribute__((address_space(1))) void*)g,
      (__attribute__((address_space(3))) void*)l, 16, 0, 0);
}

__device__ __forceinline__ float sigm(float x) { return 1.f / (1.f + expf(-x)); }
__device__ __forceinline__ float sum4(f32x4 v) { return v[0] + v[1] + v[2] + v[3]; }
__device__ __forceinline__ float bfu2f(unsigned short u) {
  unsigned int x = ((unsigned)u) << 16;
  return __uint_as_float(x);
}

__device__ __forceinline__ void split2(float x, __hip_bfloat16& hi, __hip_bfloat16& lo) {
  hi = __float2bfloat16(x);
  lo = __float2bfloat16(x - __bfloat162float(hi));
}

// ---- flag-array grid barrier, 64B-stride slots (no false sharing) ----
__device__ __forceinline__ void gbarg(unsigned* arrive, unsigned* gen,
                                      int idxInGrp, int n, bool poller) {
  __syncthreads();
  unsigned g = __hip_atomic_load(gen, __ATOMIC_RELAXED, __HIP_MEMORY_SCOPE_AGENT);
  if (threadIdx.x == 0)
    __hip_atomic_store(arrive + idxInGrp * 16, g + 1u, __ATOMIC_RELEASE, __HIP_MEMORY_SCOPE_AGENT);
  if (poller) {
    int i = threadIdx.x;
    if (i < n) {
      while (__hip_atomic_load(arrive + i * 16, __ATOMIC_RELAXED, __HIP_MEMORY_SCOPE_AGENT) < g + 1u)
        __builtin_amdgcn_s_sleep(1);
      (void)__hip_atomic_load(arrive + i * 16, __ATOMIC_ACQUIRE, __HIP_MEMORY_SCOPE_AGENT);
    }
    __syncthreads();
    if (threadIdx.x == 0)
      __hip_atomic_store(gen, g + 1u, __ATOMIC_RELEASE, __HIP_MEMORY_SCOPE_AGENT);
  }
  if (threadIdx.x == 0) {
    while (__hip_atomic_load(gen, __ATOMIC_RELAXED, __HIP_MEMORY_SCOPE_AGENT) < g + 1u)
      __builtin_amdgcn_s_sleep(1);
    (void)__hip_atomic_load(gen, __ATOMIC_ACQUIRE, __HIP_MEMORY_SCOPE_AGENT);
  }
  __syncthreads();
}

__global__ void k_zero(float* __restrict__ p, long n) {
  long i = (long)blockIdx.x * 256 + threadIdx.x;
  if (i < n) p[i] = 0.f;
}
__global__ void k_zero_bf(__hip_bfloat16* __restrict__ p, long n) {
  long i = (long)blockIdx.x * 256 + threadIdx.x;
  if (i < n) p[i] = __float2bfloat16(0.f);
}

__global__ void k_embed(const int* __restrict__ src, const float* __restrict__ emb,
                        float* __restrict__ x) {
  int id = blockIdx.x * 256 + threadIdx.x;
  if (id >= SS * BB * EE) return;
  int sb = id / EE, e = id % EE;
  x[id] = emb[(long)src[sb] * EE + e];
}

__global__ void k_dbperm(const float* __restrict__ db, float* __restrict__ dbp) {
  int id = blockIdx.x * 256 + threadIdx.x;
  if (id >= 4096) return;
  int u = id >> 2, g = id & 3;
  dbp[id] = db[g * 1024 + u];
}

// fp32 [rows][ld] (+col_off) -> [rows_pad][2*Kpad] bf16 hi|lo, zero pad.
// mode 0: src=r ; 1: seq-reverse per 64 ; 2: gate-perm rp=4u+g <- g*1024+u ; 3: transpose
__global__ void k_split_pad(const float* __restrict__ in, int ld_in, int col_off,
                            int Kreal, int Kpad, int rows_real, long rows_pad,
                            int mode, __hip_bfloat16* __restrict__ out) {
  long id = (long)blockIdx.x * 256 + threadIdx.x;
  if (id >= rows_pad * Kpad) return;
  long r = id / Kpad;
  int k = id % Kpad;
  float v = 0.f;
  if (r < rows_real && k < Kreal) {
    if (mode == 3) {
      v = in[(long)k * ld_in + col_off + r];
    } else {
      long sr = r;
      if (mode == 1) sr = ((49 - (r >> 6)) << 6) + (r & 63);
      else if (mode == 2) sr = (long)(r & 3) * 1024 + (r >> 2);
      v = in[sr * ld_in + col_off + k];
    }
  }
  __hip_bfloat16 hi, lo;
  split2(v, hi, lo);
  out[r * 2 * Kpad + k] = hi;
  out[r * 2 * Kpad + Kpad + k] = lo;
}

// gather emb_de[trg[t,b]] -> split [3200][2*320]
__global__ void k_embgather_split(const int* __restrict__ trg, const float* __restrict__ emb,
                                  __hip_bfloat16* __restrict__ out) {
  long id = (long)blockIdx.x * 256 + threadIdx.x;
  if (id >= 3200L * 320) return;
  long r = id / 320;
  int k = id % 320;
  int t = r >> 6, b = r & 63;
  float v = 0.f;
  if (t < TT - 1 && k < EE) v = emb[(long)trg[t * BB + b] * EE + k];
  __hip_bfloat16 hi, lo;
  split2(v, hi, lo);
  out[r * 640 + k] = hi;
  out[r * 640 + 320 + k] = lo;
}

// plain bf16 with zero row padding (generator weight)
__global__ void k_tobf16_pad(const float* __restrict__ W, __hip_bfloat16* __restrict__ Wb,
                             long nrow_real, long nrow_pad, int K) {
  long id = (long)blockIdx.x * 256 + threadIdx.x;
  if (id >= nrow_pad * K) return;
  long r = id / K;
  Wb[id] = __float2bfloat16(r < nrow_real ? W[id] : 0.f);
}

// repack HsWo1 [3200][1024] fp32 -> HsWo1T [256 colblk][3200 row][4] bf16
__global__ void k_repackT(const float* __restrict__ in, __hip_bfloat16* __restrict__ out) {
  long id = (long)blockIdx.x * 256 + threadIdx.x;
  if (id >= 3200L * 1024) return;
  long r = id >> 10;
  int n = id & 1023;
  out[((long)(n >> 2) * 3200 + r) * 4 + (n & 3)] = __float2bfloat16(in[id]);
}

// ---- generic split-bf16 MFMA GEMM (3-pass: AhWh + AlWh + AhWl), 128x128 tile ----
template<int OUTBF>
__global__ __launch_bounds__(256) void k_gsplit(
    const __hip_bfloat16* __restrict__ A2, const __hip_bfloat16* __restrict__ W2,
    const float* __restrict__ bias, void* __restrict__ Cout,
    int Mreal, int Nreal, int ldc, int Kpad) {
  __shared__ __hip_bfloat16 As[128 * 32];
  __shared__ __hip_bfloat16 Bs[128 * 32];
  int tid = threadIdx.x, lane = tid & 63, w = tid >> 6;
  long m0 = (long)blockIdx.y * 128, n0 = (long)blockIdx.x * 128;
  int lda2 = 2 * Kpad;
  int srow = lane >> 2;
  int scol = (lane & 3) * 8;
  char* lA0 = (char*)As + w * 2048;
  char* lA1 = lA0 + 1024;
  char* lB0 = (char*)Bs + w * 2048;
  char* lB1 = lB0 + 1024;
  int wm = (w >> 1) * 64, wn = (w & 1) * 64;
  int fr = lane & 15;
  int kc = (lane >> 4) * 8;
  f32x4 acc[4][4] = {};

  for (int seg = 0; seg < 3; ++seg) {
    const __hip_bfloat16* Ab = A2 + (seg == 1 ? Kpad : 0);
    const __hip_bfloat16* Wb = W2 + (seg == 2 ? Kpad : 0);
    const __hip_bfloat16* gA0 = Ab + (m0 + w * 32 + srow) * (long)lda2 + scol;
    const __hip_bfloat16* gA1 = gA0 + 16L * lda2;
    const __hip_bfloat16* gB0 = Wb + (n0 + w * 32 + srow) * (long)lda2 + scol;
    const __hip_bfloat16* gB1 = gB0 + 16L * lda2;
    for (int kt = 0; kt < Kpad / 32; ++kt) {
      int k0 = kt * 32;
      glds16(gA0 + k0, lA0);
      glds16(gA1 + k0, lA1);
      glds16(gB0 + k0, lB0);
      glds16(gB1 + k0, lB1);
      __syncthreads();
      bf16x8 a[4], b[4];
      for (int mi = 0; mi < 4; ++mi)
        a[mi] = *(const bf16x8*)(As + (wm + mi * 16 + fr) * 32 + kc);
      for (int ni = 0; ni < 4; ++ni)
        b[ni] = *(const bf16x8*)(Bs + (wn + ni * 16 + fr) * 32 + kc);
      for (int mi = 0; mi < 4; ++mi)
        for (int ni = 0; ni < 4; ++ni)
          acc[mi][ni] = __builtin_amdgcn_mfma_f32_16x16x32_bf16(a[mi], b[ni], acc[mi][ni], 0, 0, 0);
      __syncthreads();
    }
  }

  for (int mi = 0; mi < 4; ++mi) {
    for (int ni = 0; ni < 4; ++ni) {
      int n = (int)n0 + wn + ni * 16 + (lane & 15);
      if (n >= Nreal) continue;
      float bv = bias ? bias[n] : 0.f;
      for (int r = 0; r < 4; ++r) {
        int m = (int)m0 + wm + mi * 16 + (lane >> 4) * 4 + r;
        if (m >= Mreal) continue;
        float v = acc[mi][ni][r] + bv;
        if (OUTBF) ((__hip_bfloat16*)Cout)[(long)m * ldc + n] = __float2bfloat16(v);
        else ((float*)Cout)[(long)m * ldc + n] = v;
      }
    }
  }
}

// ---- persistent encoder: Whh in LDS, split per-direction barriers ----
__global__ __launch_bounds__(512) void persist_enc(
    const float* __restrict__ xW_f, const float* __restrict__ xW_b,
    const float* __restrict__ Whf, const float* __restrict__ Whb,
    float* __restrict__ hs, float* hA, float* hB, float* hA2, float* hB2,
    float* __restrict__ cf, float* __restrict__ cb,
    float* __restrict__ hd0, float* __restrict__ hT0, float* __restrict__ cdD,
    __hip_bfloat16* __restrict__ x2A, unsigned* __restrict__ bar) {
  __shared__ float WL[16 * 516];
  int t = threadIdx.x;
  int blk = blockIdx.x;
  int dir = blk >> 7, bl = blk & 127;
  const float* Whh = dir ? Whb : Whf;
  const float* xWb0 = dir ? xW_b : xW_f;
  float* c = dir ? cb : cf;
  float* hp = dir ? hA2 : hA;
  float* hn = dir ? hB2 : hB;
  unsigned* arrG = bar + dir * 2048;
  unsigned* genG = bar + 12288 + dir * 16;
  unsigned* arrA = bar + 4096;
  unsigned* genA = bar + 12320;

  for (int idx = t; idx < 16 * 512; idx += 512) {
    int r = idx >> 9, k = idx & 511;
    int srcrow = (r & 3) * 512 + (bl * 4 + (r >> 2));
    WL[r * 516 + k] = Whh[(long)srcrow * 512 + k];
  }
  __syncthreads();

  int j = t & 15;
  int b0 = t >> 4, b1 = b0 + 32;
  int g = j & 3;
  int ju = bl * 4 + (j >> 2);
  int lbase = (t & 63) & ~3;
  const f32x4* wq = (const f32x4*)(WL + j * 516);

  for (int s = 0; s < SS; ++s) {
    const f32x4* h0q = (const f32x4*)(hp + b0 * 512);
    const f32x4* h1q = (const f32x4*)(hp + b1 * 512);
    f32x4 v0 = {0, 0, 0, 0}, v1 = {0, 0, 0, 0};
    for (int q = 0; q < 128; ++q) {
      f32x4 wv = wq[q];
      v0 += wv * h0q[q];
      v1 += wv * h1q[q];
    }
    const float* xW = xWb0 + (long)(s * BB) * 2048;
    float a0 = sum4(v0) + xW[b0 * 2048 + g * 512 + ju];
    float a1 = sum4(v1) + xW[b1 * 2048 + g * 512 + ju];
    float gi0 = __shfl(a0, lbase + 0), gf0 = __shfl(a0, lbase + 1);
    float gg0 = __shfl(a0, lbase + 2), go0 = __shfl(a0, lbase + 3);
    float gi1 = __shfl(a1, lbase + 0), gf1 = __shfl(a1, lbase + 1);
    float gg1 = __shfl(a1, lbase + 2), go1 = __shfl(a1, lbase + 3);
    if ((t & 3) == 0) {
      int hscol = dir ? (512 + ju) : ju;
      int srow = dir ? (SS - 1 - s) : s;
      long hsrow0 = (long)(srow * BB + b0) * DH + hscol;
      long hsrow1 = (long)(srow * BB + b1) * DH + hscol;
      float cn0 = sigm(gf0) * c[b0 * 512 + ju] + sigm(gi0) * tanhf(gg0);
      float hn0 = sigm(go0) * tanhf(cn0);
      c[b0 * 512 + ju] = cn0;
      hn[b0 * 512 + ju] = hn0;
      hs[hsrow0] = hn0;
      float cn1 = sigm(gf1) * c[b1 * 512 + ju] + sigm(gi1) * tanhf(gg1);
      float hn1 = sigm(go1) * tanhf(cn1);
      c[b1 * 512 + ju] = cn1;
      hn[b1 * 512 + ju] = hn1;
      hs[hsrow1] = hn1;
    }
    float* tmp = hp; hp = hn; hn = tmp;
    gbarg(arrG, genG, bl, 128, bl == 0);
  }
  gbarg(arrA, genA, blk, 256, blk == 0);
  int gid = blk * 512 + t;
  if (gid < 65536) {
    int d2 = gid >> 15, b = (gid >> 9) & 63, j2 = gid & 511;
    float hv = (d2 ? hA2 : hA)[b * 512 + j2];
    float cv = (d2 ? cb : cf)[b * 512 + j2];
    hd0[gid] = hv;
    cdD[gid] = cv;
    int bp = gid >> 10, jp = gid & 1023;
    hT0[jp * 64 + bp] = hv;
    __hip_bfloat16 hi, lo;
    split2(hv, hi, lo);
    x2A[bp * 4096 + 1024 + jp] = hi;
    x2A[bp * 4096 + 3072 + jp] = lo;
  }
}

// ---- persistent decoder v3b (measured-best structure + bf16 G / HsWo1T) ----
// S (200 blocks, contiguous G_bf rows) ∥ TC1 -> bar -> TC2 (inline softmax+slab)
// -> bar -> G (MFMA, direct-global A-frags, LDS W, in-block C-reduce + LSTM) -> bar.
__global__ __launch_bounds__(1024) void persist_dec(
    const __hip_bfloat16* __restrict__ G, const __hip_bfloat16* __restrict__ HsWo1T,
    const float* __restrict__ Wo, const float* __restrict__ dWih,
    const float* __restrict__ dWhh, const __hip_bfloat16* __restrict__ Eg,
    float* hd0, float* hd1, float* hT0, float* hT1,
    float* __restrict__ cd, float* __restrict__ scoresG,
    __hip_bfloat16* __restrict__ A_bf,
    __hip_bfloat16* __restrict__ xA, __hip_bfloat16* __restrict__ xB,
    unsigned* __restrict__ bar) {
  __shared__ __hip_bfloat16 WB[65536];  // 128 KB split-bf16 W slice
  __shared__ float Abuf[4096];          //  16 KB: TC red ∪ C red
  int t = threadIdx.x;
  int blk = blockIdx.x;
  int w = t >> 6, lane = t & 63;
  unsigned* arrive = bar + 8192;
  unsigned* gen = bar + 12336;
  bool pol = (blk == 255);

  for (int idx = t; idx < 16 * 2048; idx += 1024) {
    int jj = idx >> 11;
    int k = idx & 2047;
    int rp2 = blk * 16 + jj;
    long srcrow = (long)(rp2 & 3) * 1024 + (rp2 >> 2);
    float v = (k < 1024) ? dWih[srcrow * 1324 + k] : dWhh[srcrow * 1024 + (k - 1024)];
    __hip_bfloat16 hi, lo;
    split2(v, hi, lo);
    WB[((k >> 3) * 16 + jj) * 8 + (k & 7)] = hi;
    WB[(((k + 2048) >> 3) * 16 + jj) * 8 + (k & 7)] = lo;
  }
  __syncthreads();

  float* hcur = hd0; float* hnew = hd1;
  float* hTc = hT0;  float* hTn = hT1;
  int j = t & 15, b = t >> 4;
  int rp = blk * 16 + j;
  int ju = blk * 4 + (j >> 2);
  int lbase = lane & ~3;
  const unsigned short* hwb = (const unsigned short*)HsWo1T + (long)blk * 3200 * 4;
  f32x4* Abuf4 = (f32x4*)Abuf;
  const float* wo2 = Wo + (long)(blk * 4) * 2048 + 1024;
  int mt = w & 3, kg = w >> 2;
  int row_a = mt * 16 + (lane & 15);
  int kq = lane >> 4;

  for (int ts = 0; ts < TT - 1; ++ts) {
    const __hip_bfloat16* xc = (ts & 1) ? xB : xA;
    __hip_bfloat16* xn = (ts & 1) ? xA : xB;
    float eg = __bfloat162float(Eg[((long)(ts * BB + b)) * 4096 + rp]);

    // ---- Phase S (200 blocks): block (s, b-quad); one wave per b-row; bf16 G ----
    if (blk < 200) {
      int s = blk >> 2;
      int bb = (blk & 3) * 16 + (t >> 6);
      int ln = t & 63;
      const u16x4* gq = (const u16x4*)((const unsigned short*)G + ((long)s * 64 + bb) * 1024);
      const f32x4* hq = (const f32x4*)(hcur + bb * 1024);
      f32x4 a4 = {0, 0, 0, 0};
      #pragma unroll
      for (int q = 0; q < 4; ++q) {
        u16x4 gu = gq[ln + q * 64];
        f32x4 gv = {bfu2f(gu[0]), bfu2f(gu[1]), bfu2f(gu[2]), bfu2f(gu[3])};
        a4 += gv * hq[ln + q * 64];
      }
      float p = sum4(a4);
      for (int o = 1; o < 64; o <<= 1) p += __shfl_xor(p, o);
      if (ln == 0) scoresG[s * 64 + bb] = p;
    }
    // ---- TC1 (all blocks): z1 = h @ Wo2 partials -> Abuf ----
    {
      f32x4 z1 = {0, 0, 0, 0};
      for (int k = w * 64; k < w * 64 + 64; ++k) {
        float hb = hTc[k * 64 + lane];
        f32x4 wv = {wo2[k], wo2[2048 + k], wo2[4096 + k], wo2[6144 + k]};
        z1 += hb * wv;
      }
      Abuf4[w * 64 + lane] = z1;
    }
    gbarg(arrive, gen, blk, 256, pol);

    // ---- TC2: inline softmax + attw slab (bf16 HsWo1T); ct -> xc (split) ----
    {
      f32x4 z2 = {0, 0, 0, 0};
      for (int s = w; s < SS; s += 16) {
        float sc = scoresG[s * 64 + lane];
        float m = sc;
        for (int o = 32; o > 0; o >>= 1) m = fmaxf(m, __shfl_xor(m, o));
        float e = expf(sc - m);
        float su = e;
        for (int o = 32; o > 0; o >>= 1) su += __shfl_xor(su, o);
        const unsigned short* u4 = hwb + ((long)s * 64 + lane) * 4;
        f32x4 hv = {bfu2f(u4[0]), bfu2f(u4[1]), bfu2f(u4[2]), bfu2f(u4[3])};
        z2 += (e / su) * hv;
      }
      Abuf4[w * 64 + lane] += z2;
      __syncthreads();
      if (t < 256) {
        int bb = t >> 2, nl = t & 3;
        float sv = 0.f;
        for (int i = 0; i < 16; ++i) sv += Abuf[(i * 64 + bb) * 4 + nl];
        float ct = tanhf(sv);
        __hip_bfloat16 hi, lo;
        split2(ct, hi, lo);
        ((__hip_bfloat16*)xc)[bb * 4096 + blk * 4 + nl] = hi;
        ((__hip_bfloat16*)xc)[bb * 4096 + 2048 + blk * 4 + nl] = lo;
      }
    }
    gbarg(arrive, gen, blk, 256, pol);

    // ---- Phase G: 48 MFMA/wave, A-frags direct from global, W from LDS ----
    {
      f32x4 acc = {0, 0, 0, 0};
      const __hip_bfloat16* xrow = xc + (long)row_a * 4096 + kq * 8;
      for (int seg = 0; seg < 3; ++seg) {
        int aoff = (seg == 1) ? 2048 : 0;
        int woff = (seg == 2) ? 2048 : 0;
        #pragma unroll
        for (int c = 0; c < 16; ++c) {
          int kb = kg * 512 + c * 32;
          bf16x8 a = *(const bf16x8*)(xrow + aoff + kb);
          int gidx = ((woff + kb) >> 3) + kq;
          bf16x8 bfr = *(const bf16x8*)(WB + (gidx * 16 + (lane & 15)) * 8);
          acc = __builtin_amdgcn_mfma_f32_16x16x32_bf16(a, bfr, acc, 0, 0, 0);
        }
      }
      for (int r = 0; r < 4; ++r)
        Abuf[kg * 1024 + (mt * 16 + kq * 4 + r) * 16 + (lane & 15)] = acc[r];
      __syncthreads();
      float gv = Abuf[t] + Abuf[1024 + t] + Abuf[2048 + t] + Abuf[3072 + t] + eg;
      float gi0 = __shfl(gv, lbase + 0), gf0 = __shfl(gv, lbase + 1);
      float gg0 = __shfl(gv, lbase + 2), go0 = __shfl(gv, lbase + 3);
      if ((t & 3) == 0) {
        float cn0 = sigm(gf0) * cd[b * DH + ju] + sigm(gi0) * tanhf(gg0);
        float hn0 = sigm(go0) * tanhf(cn0);
        cd[b * DH + ju] = cn0;
        hnew[b * DH + ju] = hn0;
        hTn[ju * 64 + b] = hn0;
        __hip_bfloat16 hi, lo;
        split2(hn0, hi, lo);
        A_bf[(long)ts * (BB * DH) + b * DH + ju] = hi;
        xn[b * 4096 + 1024 + ju] = hi;
        xn[b * 4096 + 3072 + ju] = lo;
      }
    }
    { float* x = hcur; hcur = hnew; hnew = x; }
    { float* x = hTc; hTc = hTn; hTn = x; }
    gbarg(arrive, gen, blk, 256, pol);
  }
}

// ---- bf16 MFMA generator GEMM (128x128 tile, m97 structure) ----
__global__ __launch_bounds__(256) void k_gen_mfma(
    const __hip_bfloat16* __restrict__ A, const __hip_bfloat16* __restrict__ Bw,
    const float* __restrict__ bias, float* __restrict__ C) {
  __shared__ __hip_bfloat16 As[128 * 32];
  __shared__ __hip_bfloat16 Bs[128 * 32];
  int tid = threadIdx.x;
  int lane = tid & 63, w = tid >> 6;
  long m0 = (long)blockIdx.y * 128, n0 = (long)blockIdx.x * 128;
  int srow = lane >> 2;
  int scol = (lane & 3) * 8;
  const __hip_bfloat16* gA0 = A + (m0 + w * 32 + srow) * GK + scol;
  const __hip_bfloat16* gA1 = gA0 + 16 * GK;
  const __hip_bfloat16* gB0 = Bw + (n0 + w * 32 + srow) * GK + scol;
  const __hip_bfloat16* gB1 = gB0 + 16 * GK;
  char* lA0 = (char*)As + w * 2048;
  char* lA1 = lA0 + 1024;
  char* lB0 = (char*)Bs + w * 2048;
  char* lB1 = lB0 + 1024;
  int wm = (w >> 1) * 64, wn = (w & 1) * 64;
  int fr = lane & 15;
  int kc = (lane >> 4) * 8;
  f32x4 acc[4][4] = {};
  for (int kt = 0; kt < GK / 32; ++kt) {
    int k0 = kt * 32;
    glds16(gA0 + k0, lA0);
    glds16(gA1 + k0, lA1);
    glds16(gB0 + k0, lB0);
    glds16(gB1 + k0, lB1);
    __syncthreads();
    bf16x8 a[4], b[4];
    for (int mi = 0; mi < 4; ++mi)
      a[mi] = *(const bf16x8*)(As + (wm + mi * 16 + fr) * 32 + kc);
    for (int ni = 0; ni < 4; ++ni)
      b[ni] = *(const bf16x8*)(Bs + (wn + ni * 16 + fr) * 32 + kc);
    for (int mi = 0; mi < 4; ++mi)
      for (int ni = 0; ni < 4; ++ni)
        acc[mi][ni] = __builtin_amdgcn_mfma_f32_16x16x32_bf16(a[mi], b[ni], acc[mi][ni], 0, 0, 0);
    __syncthreads();
  }
  for (int mi = 0; mi < 4; ++mi) {
    for (int ni = 0; ni < 4; ++ni) {
      int n = (int)n0 + wn + ni * 16 + (lane & 15);
      if (n >= GNRE) continue;
      float bv = bias[n];
      for (int r = 0; r < 4; ++r) {
        int m = (int)m0 + wm + mi * 16 + (lane >> 4) * 4 + r;
        if (m < GMRE) C[(long)m * TRGV + n] = acc[mi][ni][r] + bv;
      }
    }
  }
}

// in-place log-softmax over vocab for rows 64..3199 of out
__global__ __launch_bounds__(256) void k_logsoftmax(float* __restrict__ out) {
  int r = blockIdx.x;
  float* p = out + (long)(BB + r) * TRGV;
  int tid = threadIdx.x;
  __shared__ float red[256];
  float m = -1e30f;
  for (int i = tid; i < TRGV; i += 256) m = fmaxf(m, p[i]);
  red[tid] = m;
  __syncthreads();
  for (int s = 128; s > 0; s >>= 1) {
    if (tid < s) red[tid] = fmaxf(red[tid], red[tid + s]);
    __syncthreads();
  }
  m = red[0];
  __syncthreads();
  float sum = 0.f;
  for (int i = tid; i < TRGV; i += 256) sum += expf(p[i] - m);
  red[tid] = sum;
  __syncthreads();
  for (int s = 128; s > 0; s >>= 1) {
    if (tid < s) red[tid] += red[tid + s];
    __syncthreads();
  }
  float lse = m + logf(red[0]);
  for (int i = tid; i < TRGV; i += 256) p[i] -= lse;
}

extern "C" void kernel_launch(void* const* d_in, const int* in_sizes, int n_in,
                              void* d_out, int out_size, void* d_ws, size_t ws_size,
                              hipStream_t stream) {
  const int* src = (const int*)d_in[0];
  const int* trg = (const int*)d_in[1];
  const float* emb_en = (const float*)d_in[2];
  const float* emb_de = (const float*)d_in[3];
  const float* eWih_f = (const float*)d_in[4];
  const float* eWhh_f = (const float*)d_in[5];
  const float* eb_f = (const float*)d_in[6];
  const float* eWih_b = (const float*)d_in[7];
  const float* eWhh_b = (const float*)d_in[8];
  const float* eb_b = (const float*)d_in[9];
  const float* dWih = (const float*)d_in[10];
  const float* dWhh = (const float*)d_in[11];
  const float* db = (const float*)d_in[12];
  const float* Wgen = (const float*)d_in[13];
  const float* bgen = (const float*)d_in[14];
  const float* Wi = (const float*)d_in[15];
  const float* Wo = (const float*)d_in[16];
  float* out = (float*)d_out;

  float* base = (float*)d_ws;
  // ---- region RA (16,465,920 floats, time-multiplexed) ----
  __hip_bfloat16* xsf = (__hip_bfloat16*)base;
  __hip_bfloat16* xsb = (__hip_bfloat16*)(base + 1024000);
  __hip_bfloat16* Wihf2 = (__hip_bfloat16*)(base + 2048000);
  __hip_bfloat16* Wihb2 = (__hip_bfloat16*)(base + 2703360);
  float* xW_f = base + 3358720;
  float* xW_b = base + 9912320;
  __hip_bfloat16* hs2 = (__hip_bfloat16*)base;
  __hip_bfloat16* Wi2 = (__hip_bfloat16*)(base + 3276800);
  __hip_bfloat16* Wo12 = (__hip_bfloat16*)(base + 4325376);
  __hip_bfloat16* eg2 = (__hip_bfloat16*)(base + 5373952);
  __hip_bfloat16* Wce2 = (__hip_bfloat16*)(base + 6397952);
  __hip_bfloat16* E_g = (__hip_bfloat16*)(base + 7708672);
  __hip_bfloat16* Wgen_bf = (__hip_bfloat16*)base;   // phase 3
  // ---- region RB (persistent) ----
  float* p = base + 16465920;
  float* x_enc = p; p += SS * BB * EE;
  float* hs = p; p += (long)SS * BB * DH;
  __hip_bfloat16* G_bf = (__hip_bfloat16*)p; p += (long)SS * BB * DH / 2;
  float* HsWo1 = p; p += (long)SS * BB * DH;
  __hip_bfloat16* HsWo1T = (__hip_bfloat16*)p; p += (long)SS * BB * DH / 2;
  __hip_bfloat16* A_bf = (__hip_bfloat16*)p; p += (GMP * GK) / 2;
  __hip_bfloat16* x2A = (__hip_bfloat16*)p; p += (BB * 4096) / 2;
  __hip_bfloat16* x2B = (__hip_bfloat16*)p; p += (BB * 4096) / 2;
  float* dbp = p; p += 4096;
  float* scoresG = p; p += SS * BB;
  float* hd0 = p; p += BB * DH;
  float* hd1 = p; p += BB * DH;
  float* hT0 = p; p += BB * DH;
  float* hT1 = p; p += BB * DH;
  float* cd = p; p += BB * DH;
  float* hA = p; p += BB * EH;
  float* hB = p; p += BB * EH;
  float* hA2 = p; p += BB * EH;
  float* hB2 = p; p += BB * EH;
  float* cf = p; p += BB * EH;
  float* cb = p; p += BB * EH;
  unsigned* bar = (unsigned*)p; p += 12352;

  dim3 b256(256);

  // ---- setup ----
  k_embed<<<dim3((SS * BB * EE + 255) / 256), b256, 0, stream>>>(src, emb_en, x_enc);
  k_zero<<<dim3((6 * BB * EH + 255) / 256), b256, 0, stream>>>(hA, 6 * BB * EH);
  k_zero<<<dim3(49), b256, 0, stream>>>((float*)bar, 12352);
  k_zero<<<dim3((int)(((long)BB * TRGV + 255) / 256)), b256, 0, stream>>>(out, (long)BB * TRGV);
  k_zero_bf<<<dim3(((GMP - GMRE) * GK + 255) / 256), b256, 0, stream>>>(
      A_bf + (long)GMRE * GK, (long)(GMP - GMRE) * GK);
  k_dbperm<<<dim3(16), b256, 0, stream>>>(db, dbp);

  // ---- encoder input: splits + split-MFMA GEMMs ----
  k_split_pad<<<dim3((3200 * 320 + 255) / 256), b256, 0, stream>>>(
      x_enc, EE, 0, EE, 320, 3200, 3200, 0, xsf);
  k_split_pad<<<dim3((3200 * 320 + 255) / 256), b256, 0, stream>>>(
      x_enc, EE, 0, EE, 320, 3200, 3200, 1, xsb);
  k_split_pad<<<dim3((2048 * 320 + 255) / 256), b256, 0, stream>>>(
      eWih_f, EE, 0, EE, 320, 2048, 2048, 0, Wihf2);
  k_split_pad<<<dim3((2048 * 320 + 255) / 256), b256, 0, stream>>>(
      eWih_b, EE, 0, EE, 320, 2048, 2048, 0, Wihb2);
  k_gsplit<0><<<dim3(16, 25), b256, 0, stream>>>(xsf, Wihf2, eb_f, xW_f, 3200, 2048, 2048, 320);
  k_gsplit<0><<<dim3(16, 25), b256, 0, stream>>>(xsb, Wihb2, eb_b, xW_b, 3200, 2048, 2048, 320);

  // ---- persistent encoder ----
  {
    void* args[] = {(void*)&xW_f, (void*)&xW_b, (void*)&eWhh_f, (void*)&eWhh_b,
                    (void*)&hs, (void*)&hA, (void*)&hB, (void*)&hA2, (void*)&hB2,
                    (void*)&cf, (void*)&cb, (void*)&hd0, (void*)&hT0, (void*)&cd,
                    (void*)&x2A, (void*)&bar};
    hipLaunchCooperativeKernel((const void*)persist_enc, dim3(256), dim3(512),
                               args, 0, stream);
  }

  // ---- decoder-loop hoists: G (bf16), HsWo1(+bf16 repack), E_gates ----
  k_split_pad<<<dim3((int)((3200L * 1024 + 255) / 256)), b256, 0, stream>>>(
      hs, DH, 0, DH, 1024, 3200, 3200, 0, hs2);
  k_split_pad<<<dim3((int)((1024L * 1024 + 255) / 256)), b256, 0, stream>>>(
      Wi, DH, 0, DH, 1024, 1024, 1024, 3, Wi2);
  k_split_pad<<<dim3((int)((1024L * 1024 + 255) / 256)), b256, 0, stream>>>(
      Wo, 2 * DH, 0, DH, 1024, 1024, 1024, 0, Wo12);
  k_embgather_split<<<dim3((int)((3200L * 320 + 255) / 256)), b256, 0, stream>>>(
      trg, emb_de, eg2);
  k_split_pad<<<dim3((int)((4096L * 320 + 255) / 256)), b256, 0, stream>>>(
      dWih, 1324, 1024, EE, 320, 4096, 4096, 2, Wce2);
  k_gsplit<1><<<dim3(8, 25), b256, 0, stream>>>(hs2, Wi2, (const float*)nullptr, G_bf, 3200, 1024, 1024, 1024);
  k_gsplit<0><<<dim3(8, 25), b256, 0, stream>>>(hs2, Wo12, (const float*)nullptr, HsWo1, 3200, 1024, 1024, 1024);
  k_repackT<<<dim3((int)((3200L * 1024 + 255) / 256)), b256, 0, stream>>>(HsWo1, HsWo1T);
  k_gsplit<1><<<dim3(32, 25), b256, 0, stream>>>(eg2, Wce2, dbp, E_g, 3136, 4096, 4096, 320);

  // ---- persistent decoder ----
  {
    void* args[] = {(void*)&G_bf, (void*)&HsWo1T, (void*)&Wo, (void*)&dWih, (void*)&dWhh,
                    (void*)&E_g, (void*)&hd0, (void*)&hd1, (void*)&hT0, (void*)&hT1,
                    (void*)&cd, (void*)&scoresG, (void*)&A_bf, (void*)&x2A, (void*)&x2B,
                    (void*)&bar};
    hipLaunchCooperativeKernel((const void*)persist_dec, dim3(256), dim3(1024),
                               args, 0, stream);
  }

  // ---- generator ----
  k_tobf16_pad<<<dim3((int)(((long)GNP * GK + 255) / 256)), b256, 0, stream>>>(
      Wgen, Wgen_bf, GNRE, GNP, GK);
  k_gen_mfma<<<dim3(GNP / 128, GMP / 128), b256, 0, stream>>>(
      A_bf, Wgen_bf, bgen, out + (long)BB * TRGV);
  k_logsoftmax<<<dim3((TT - 1) * BB), b256, 0, stream>>>(out);
}